// Round 3
// baseline (16700.504 us; speedup 1.0000x reference)
//
#include <hip/hip_runtime.h>
#include <hip/hip_bf16.h>
#include <math.h>

// Problem constants
#define I_DIM 64
#define H_DIM 256
#define NC    10
#define S1    500
#define S2    41
#define BATCH 128
#define ST    (S1 + S2)          // 541
#define F1    (ST * H_DIM)       // 138496
#define G4H   (4 * H_DIM)        // 1024 gate rows
#define KTOT  (I_DIM + H_DIM)    // 320
#define K4TOT (KTOT / 4)         // 80
#define NSL   8                  // k-slices
#define K4PS  (K4TOT / NSL)      // 10 float4-k per slice

// fc1 split-K params
#define KC   512
#define KCH  32
#define NSLICE ((F1 + KC - 1) / KC)   // 271

__device__ __forceinline__ float sigmoidf(float x) {
    return 1.0f / (1.0f + __expf(-x));
}
__device__ __forceinline__ float tanh_fast(float x) {
    // (e^2x - 1)/(e^2x + 1), robust at +/-inf of expf
    float e = __expf(2.0f * x);
    return 1.0f - 2.0f / (e + 1.0f);
}

// ---------------------------------------------------------------------------
// Pack [w_ih | w_hh] into k-major float4 layout grouped per owner thread:
//   row index r = u2*8 + b*4 + gate   (u2 = unit pair, unit = 2*u2+b)
//   Wp[l][k4][r] = float4( wcat[gate*256+unit][4k4 .. 4k4+3] )
// so thread (u2,s) reads 8 contiguous float4s (128B) per k4 — its 2 units'
// 4 gate rows. bsum[l][g_orig] = b_ih + b_hh.
// ---------------------------------------------------------------------------
__global__ void prep_pack(const float* __restrict__ wih1, const float* __restrict__ whh1,
                          const float* __restrict__ bih1, const float* __restrict__ bhh1,
                          const float* __restrict__ wih2, const float* __restrict__ whh2,
                          const float* __restrict__ bih2, const float* __restrict__ bhh2,
                          float4* __restrict__ Wp, float* __restrict__ bsum) {
    int gid = blockIdx.x * blockDim.x + threadIdx.x;   // 0..2047
    if (gid >= 2 * G4H) return;
    int l  = gid >> 10;
    int r  = gid & 1023;
    int u2 = r >> 3, j = r & 7;
    int bb = j >> 2, g = j & 3;
    int unit = 2 * u2 + bb;
    int g_orig = g * 256 + unit;
    const float* wih = l ? wih2 : wih1;
    const float* whh = l ? whh2 : whh1;
    float4* dst = Wp + (size_t)l * K4TOT * G4H;
    for (int k4 = 0; k4 < K4TOT; ++k4) {
        int k = 4 * k4;
        float4 v;
        if (k < I_DIM) {
            const float* p = wih + (size_t)g_orig * I_DIM + k;
            v = make_float4(p[0], p[1], p[2], p[3]);
        } else {
            const float* p = whh + (size_t)g_orig * H_DIM + (k - I_DIM);
            v = make_float4(p[0], p[1], p[2], p[3]);
        }
        dst[(size_t)k4 * G4H + r] = v;
    }
    bsum[l * G4H + g_orig] = l ? (bih2[g_orig] + bhh2[g_orig])
                               : (bih1[g_orig] + bhh1[g_orig]);
}

// ---------------------------------------------------------------------------
// Register-resident-weight peephole LSTM.
// Grid: 256 blocks x 1024 threads; block wg: l = wg>>7, batch b = wg&127.
// Thread (u2 = tid&127, s = tid>>7): owns units {2u2, 2u2+1} x 4 gates for
// k-slice [40s, 40s+40) — 80 float4 weights IN REGISTERS (loaded once).
// Per step: 10 broadcast LDS reads of [x_t|h_{t-1}] + 320 FMAs; partials to
// LDS; threads tid<256 reduce 8 slices + peephole activation for unit tid.
// ---------------------------------------------------------------------------
__global__ __launch_bounds__(1024, 4) void lstm_fused(
        const float* __restrict__ x1, const float* __restrict__ x2,
        const float* __restrict__ wci1, const float* __restrict__ wcf1, const float* __restrict__ wco1,
        const float* __restrict__ wci2, const float* __restrict__ wcf2, const float* __restrict__ wco2,
        const float4* __restrict__ Wp, const float* __restrict__ bsum,
        float* __restrict__ hseq) {
    const int wg = blockIdx.x;        // 0..255
    const int l  = wg >> 7;           // 0 or 1
    const int b  = wg & 127;          // batch element
    const int T    = l ? S2 : S1;
    const int toff = l ? S1 : 0;
    const float* x   = l ? x2 : x1;
    const float* wci = l ? wci2 : wci1;
    const float* wcf = l ? wcf2 : wcf1;
    const float* wco = l ? wco2 : wco1;

    const int tid = threadIdx.x;
    const int u2  = tid & 127;        // unit pair
    const int s   = tid >> 7;         // k-slice 0..7 (wave-uniform)

    __shared__ __align__(16) float  vbuf[2][KTOT];            // [x|h], double buf
    __shared__ __align__(16) float4 part4[NSL * 2 * 128];     // slice partials

    // zero vbuf (h of buf0 must be 0; buf1 gets overwritten before use)
    for (int i = tid; i < 2 * KTOT; i += 1024) ((float*)vbuf)[i] = 0.f;
    __syncthreads();
    // stage x_0
    if (tid < 16) {
        float4 v = *(const float4*)(x + ((size_t)b * T + 0) * I_DIM + 4 * tid);
        *((float4*)&vbuf[0][4 * tid]) = v;
    }

    // one-time: weights into registers (80 float4 = 320 VGPRs)
    float4 wreg[K4PS][8];
    const float4* Wb = Wp + (size_t)l * K4TOT * G4H
                          + (size_t)(K4PS * s) * G4H + (size_t)u2 * 8;
    #pragma unroll
    for (int k4 = 0; k4 < K4PS; ++k4)
        #pragma unroll
        for (int j = 0; j < 8; ++j)
            wreg[k4][j] = Wb[(size_t)k4 * G4H + j];

    // reducer-thread constants (thread tid<256 owns unit u=tid)
    float bI = 0.f, bF = 0.f, bG = 0.f, bO = 0.f;
    float pi = 0.f, pf = 0.f, po = 0.f, c = 0.f;
    if (tid < H_DIM) {
        bI = bsum[l * G4H + tid];
        bF = bsum[l * G4H + 256 + tid];
        bG = bsum[l * G4H + 512 + tid];
        bO = bsum[l * G4H + 768 + tid];
        pi = wci[tid]; pf = wcf[tid]; po = wco[tid];
    }
    const int sel = tid & 1;          // reducer: which float4 half
    const int u2r = (tid & 255) >> 1; // reducer: unit pair

    int cur = 0;
    __syncthreads();

    for (int t = 0; t < T; ++t) {
        const float4* vb = (const float4*)vbuf[cur];
        float acc[8];
        #pragma unroll
        for (int j = 0; j < 8; ++j) acc[j] = 0.f;

        #pragma unroll
        for (int k4 = 0; k4 < K4PS; ++k4) {
            float4 v = vb[K4PS * s + k4];      // broadcast (wave-uniform addr)
            #pragma unroll
            for (int j = 0; j < 8; ++j) {
                float4 w = wreg[k4][j];
                acc[j] = fmaf(w.x, v.x, fmaf(w.y, v.y,
                         fmaf(w.z, v.z, fmaf(w.w, v.w, acc[j]))));
            }
        }
        part4[(s * 2 + 0) * 128 + u2] = make_float4(acc[0], acc[1], acc[2], acc[3]);
        part4[(s * 2 + 1) * 128 + u2] = make_float4(acc[4], acc[5], acc[6], acc[7]);

        // prefetch x_{t+1} into the other buffer (disjoint from h region)
        if (s == 7 && u2 < 16) {
            int tt = t + 1;
            if (tt < T) {
                float4 v = *(const float4*)(x + ((size_t)b * T + tt) * I_DIM + 4 * u2);
                *((float4*)&vbuf[cur ^ 1][4 * u2]) = v;
            }
        }
        __syncthreads();

        if (tid < H_DIM) {
            float4 p = part4[sel * 128 + u2r];
            #pragma unroll
            for (int i = 1; i < NSL; ++i) {
                float4 q = part4[(i * 2 + sel) * 128 + u2r];
                p.x += q.x; p.y += q.y; p.z += q.z; p.w += q.w;
            }
            float i_ = sigmoidf(p.x + bI + pi * c);
            float f_ = sigmoidf(p.y + bF + pf * c);
            float g_ = tanh_fast(p.z + bG);
            float cy = f_ * c + i_ * g_;
            float o_ = sigmoidf(p.w + bO + po * cy);
            float hy = o_ * tanh_fast(cy);
            c = cy;
            vbuf[cur ^ 1][I_DIM + tid] = hy;
            hseq[((size_t)b * ST + toff + t) * H_DIM + tid] = hy;
        }
        __syncthreads();
        cur ^= 1;
    }
}

// ---------------------------------------------------------------------------
// fc1 split-K partial GEMM (unchanged)
// ---------------------------------------------------------------------------
__global__ __launch_bounds__(256) void fc1_partial(const float* __restrict__ hseq,
                                                   const float* __restrict__ w,
                                                   float* __restrict__ part) {
    const int s  = blockIdx.x;          // 0..NSLICE-1
    const int k0 = s * KC;
    const int kend = (k0 + KC < F1) ? (k0 + KC) : F1;

    __shared__ float As[KCH][129];      // As[k][b]
    __shared__ float Bs[KCH][129];      // Bs[k][j]

    const int tid = threadIdx.x;
    const int tx = tid & 15;            // j block
    const int ty = tid >> 4;            // b block

    float acc[8][8];
    #pragma unroll
    for (int i = 0; i < 8; ++i)
        #pragma unroll
        for (int j = 0; j < 8; ++j) acc[i][j] = 0.f;

    for (int kk = k0; kk < kend; kk += KCH) {
        #pragma unroll
        for (int r = 0; r < 16; ++r) {
            int idx = r * 256 + tid;    // 0..4095
            int row = idx >> 5;
            int k   = idx & 31;
            int gk  = kk + k;
            float av = (gk < F1) ? hseq[(size_t)row * F1 + gk] : 0.f;
            float bv = (gk < F1) ? w[(size_t)row * F1 + gk] : 0.f;
            As[k][row] = av;
            Bs[k][row] = bv;
        }
        __syncthreads();

        #pragma unroll 8
        for (int k = 0; k < KCH; ++k) {
            float av[8], bv[8];
            #pragma unroll
            for (int i = 0; i < 8; ++i) av[i] = As[k][ty * 8 + i];
            #pragma unroll
            for (int j = 0; j < 8; ++j) bv[j] = Bs[k][tx * 8 + j];
            #pragma unroll
            for (int i = 0; i < 8; ++i)
                #pragma unroll
                for (int j = 0; j < 8; ++j)
                    acc[i][j] = fmaf(av[i], bv[j], acc[i][j]);
        }
        __syncthreads();
    }

    float* dst = part + (size_t)s * (BATCH * 128);
    #pragma unroll
    for (int i = 0; i < 8; ++i)
        #pragma unroll
        for (int j = 0; j < 8; ++j)
            dst[(size_t)(ty * 8 + i) * 128 + (tx * 8 + j)] = acc[i][j];
}

__global__ __launch_bounds__(256) void fc1_reduce(const float* __restrict__ part,
                                                  const float* __restrict__ fc1_b,
                                                  float* __restrict__ out1) {
    int flat = blockIdx.x * 256 + threadIdx.x;     // 0..16383
    float sum = 0.f;
    for (int i = 0; i < NSLICE; ++i)
        sum += part[(size_t)i * (BATCH * 128) + flat];
    int j = flat & 127;
    sum += fc1_b[j];
    out1[flat] = fmaxf(sum, 0.f);
}

__global__ __launch_bounds__(128) void fc2_kernel(const float* __restrict__ out1,
                                                  const float* __restrict__ fcw,
                                                  const float* __restrict__ fcb,
                                                  float* __restrict__ out) {
    int b = blockIdx.x;
    __shared__ float ro[128];
    int tid = threadIdx.x;
    ro[tid] = out1[(size_t)b * 128 + tid];
    __syncthreads();
    if (tid < NC) {
        float s = fcb[tid];
        #pragma unroll 8
        for (int j = 0; j < 128; ++j)
            s = fmaf(ro[j], fcw[(size_t)tid * 128 + j], s);
        out[(size_t)b * NC + tid] = s;
    }
}

// ---------------------------------------------------------------------------
extern "C" void kernel_launch(void* const* d_in, const int* in_sizes, int n_in,
                              void* d_out, int out_size, void* d_ws, size_t ws_size,
                              hipStream_t stream) {
    const float* rr_x  = (const float*)d_in[0];
    const float* rr_wv = (const float*)d_in[1];
    const float* w_ih1 = (const float*)d_in[2];
    const float* w_hh1 = (const float*)d_in[3];
    const float* b_ih1 = (const float*)d_in[4];
    const float* b_hh1 = (const float*)d_in[5];
    const float* wci1  = (const float*)d_in[6];
    const float* wcf1  = (const float*)d_in[7];
    const float* wco1  = (const float*)d_in[8];
    const float* w_ih2 = (const float*)d_in[9];
    const float* w_hh2 = (const float*)d_in[10];
    const float* b_ih2 = (const float*)d_in[11];
    const float* b_hh2 = (const float*)d_in[12];
    const float* wci2  = (const float*)d_in[13];
    const float* wcf2  = (const float*)d_in[14];
    const float* wco2  = (const float*)d_in[15];
    const float* fc1_w = (const float*)d_in[16];
    const float* fc1_b = (const float*)d_in[17];
    const float* fc_w  = (const float*)d_in[18];
    const float* fc_b  = (const float*)d_in[19];
    float* out = (float*)d_out;

    char* ws = (char*)d_ws;
    size_t off = 0;
    float4* Wp   = (float4*)(ws + off); off += (size_t)2 * K4TOT * G4H * sizeof(float4);
    float*  bsum = (float*)(ws + off);  off += (size_t)2 * G4H * sizeof(float);
    float*  hseq = (float*)(ws + off);  off += (size_t)BATCH * F1 * sizeof(float);
    float*  part = (float*)(ws + off);  off += (size_t)NSLICE * BATCH * 128 * sizeof(float);
    float*  out1 = (float*)(ws + off);  off += (size_t)BATCH * 128 * sizeof(float);

    prep_pack<<<8, 256, 0, stream>>>(w_ih1, w_hh1, b_ih1, b_hh1,
                                     w_ih2, w_hh2, b_ih2, b_hh2, Wp, bsum);

    lstm_fused<<<256, 1024, 0, stream>>>(rr_x, rr_wv,
                                         wci1, wcf1, wco1, wci2, wcf2, wco2,
                                         Wp, bsum, hseq);

    fc1_partial<<<NSLICE, 256, 0, stream>>>(hseq, fc1_w, part);
    fc1_reduce<<<BATCH * 128 / 256, 256, 0, stream>>>(part, fc1_b, out1);
    fc2_kernel<<<BATCH, 128, 0, stream>>>(out1, fc_w, fc_b, out);
}

// Round 4
// 8061.786 us; speedup vs baseline: 2.0716x; 2.0716x over previous
//
#include <hip/hip_runtime.h>
#include <hip/hip_bf16.h>
#include <hip/hip_fp16.h>
#include <math.h>

// Problem constants
#define I_DIM 64
#define H_DIM 256
#define NC    10
#define S1    500
#define S2    41
#define BATCH 128
#define ST    (S1 + S2)          // 541
#define F1    (ST * H_DIM)       // 138496
#define G4H   (4 * H_DIM)        // 1024 gate rows
#define KTOT  (I_DIM + H_DIM)    // 320
#define NK8   (KTOT / 8)         // 40 8-wide k groups
#define NSL   4                  // k-slices (s = tid>>8)
#define K8PS  (NK8 / NSL)        // 10 8-k iters per slice

// fc1 split-K params
#define KC   512
#define KCH  32
#define NSLICE ((F1 + KC - 1) / KC)   // 271

typedef _Float16 h2 __attribute__((ext_vector_type(2)));
struct __align__(16) H24 { h2 x, y, z, w; };   // 8 fp16
struct __align__(8)  H22 { h2 x, y; };         // 4 fp16

#if defined(__has_builtin)
# if __has_builtin(__builtin_amdgcn_fdot2)
#  define FDOT2(a, b, c) __builtin_amdgcn_fdot2((a), (b), (c), false)
# endif
#endif
#ifndef FDOT2
# define FDOT2(a, b, c) fmaf((float)(a)[0], (float)(b)[0], \
                        fmaf((float)(a)[1], (float)(b)[1], (c)))
#endif

__device__ __forceinline__ float sigmoidf(float x) {
    return 1.0f / (1.0f + __expf(-x));
}
__device__ __forceinline__ float tanh_fast(float x) {
    float e = __expf(2.0f * x);
    return 1.0f - 2.0f / (e + 1.0f);
}

// ---------------------------------------------------------------------------
// Pack [w_ih | w_hh] into fp16, k-major, gate-then-unit layout:
//   Wh[l][k8][g][u][e] , e = 0..7 fp16 along k (k = 8*k8 + e)
// One wave's load of gate g at fixed k8 covers 64 consecutive u -> 1KB
// contiguous, perfectly coalesced. bsum[l][g_orig] = b_ih + b_hh (fp32).
// ---------------------------------------------------------------------------
__global__ void prep_pack(const float* __restrict__ wih1, const float* __restrict__ whh1,
                          const float* __restrict__ bih1, const float* __restrict__ bhh1,
                          const float* __restrict__ wih2, const float* __restrict__ whh2,
                          const float* __restrict__ bih2, const float* __restrict__ bhh2,
                          _Float16* __restrict__ Wh, float* __restrict__ bsum) {
    int gid = blockIdx.x * blockDim.x + threadIdx.x;   // 0..2047
    if (gid >= 2 * G4H) return;
    int l = gid >> 10;
    int r = gid & 1023;
    int g = r >> 8;                // gate 0..3
    int u = r & 255;               // unit
    int g_orig = g * 256 + u;      // original gate row
    const float* wih = l ? wih2 : wih1;
    const float* whh = l ? whh2 : whh1;
    _Float16* dst = Wh + (size_t)l * NK8 * 4 * 256 * 8;
    for (int k8 = 0; k8 < NK8; ++k8) {
        #pragma unroll
        for (int e = 0; e < 8; ++e) {
            int k = 8 * k8 + e;
            float v = (k < I_DIM) ? wih[(size_t)g_orig * I_DIM + k]
                                  : whh[(size_t)g_orig * H_DIM + (k - I_DIM)];
            dst[(((size_t)k8 * 4 + g) * 256 + u) * 8 + e] = (_Float16)v;
        }
    }
    bsum[l * G4H + g_orig] = l ? (bih2[g_orig] + bhh2[g_orig])
                               : (bih1[g_orig] + bhh1[g_orig]);
}

// ---------------------------------------------------------------------------
// Peephole LSTM: fp16 weights streamed from L2 with explicit double-buffered
// prefetch; fp16 [x|h] broadcast from LDS; fp32 accumulation via v_dot2.
// Grid: 128 blocks x 1024 threads. Blocks 0..63 -> LSTM1 (2 batch each),
// 64..127 -> LSTM2. Thread (u = tid&255, s = tid>>8): unit u, 4 gates,
// k-slice [80s, 80s+80), both batches. Partials via LDS; s==0 reduces +
// activations. 2 barriers/step.
// ---------------------------------------------------------------------------
__global__ __launch_bounds__(1024, 4) void lstm_fused(
        const float* __restrict__ x1, const float* __restrict__ x2,
        const float* __restrict__ wci1, const float* __restrict__ wcf1, const float* __restrict__ wco1,
        const float* __restrict__ wci2, const float* __restrict__ wcf2, const float* __restrict__ wco2,
        const _Float16* __restrict__ Wh, const float* __restrict__ bsum,
        float* __restrict__ hseq) {
    const int wg  = blockIdx.x;       // 0..127
    const int l   = wg >> 6;          // 0 or 1
    const int b0  = (wg & 63) * 2;
    const int T    = l ? S2 : S1;
    const int toff = l ? S1 : 0;
    const float* x   = l ? x2 : x1;
    const float* wci = l ? wci2 : wci1;
    const float* wcf = l ? wcf2 : wcf1;
    const float* wco = l ? wco2 : wco1;

    const int tid = threadIdx.x;
    const int u = tid & 255;          // unit
    const int s = tid >> 8;           // k-slice 0..3 (wave-uniform)

    // [x|h] in fp16, double-buffered: vh[buf][batch][k], k<64 = x, k>=64 = h
    __shared__ __align__(16) _Float16 vh[2][2][KTOT];
    // slice partials from s=1..3: part[s-1][b][gate][u]
    __shared__ float part[NSL - 1][2][4][H_DIM];

    // zero vh (h region of buf0 must be 0 at t=0)
    if (tid < (2 * 2 * KTOT * 2) / 4) ((int*)vh)[tid] = 0;   // 640 ints
    __syncthreads();
    // stage x_0 (fp32 -> fp16)
    if (tid < 32) {
        int bb = tid >> 4, j = tid & 15;
        float4 v = *(const float4*)(x + ((size_t)(b0 + bb) * T + 0) * I_DIM + 4 * j);
        H22 p;
        p.x = h2{(_Float16)v.x, (_Float16)v.y};
        p.y = h2{(_Float16)v.z, (_Float16)v.w};
        *(H22*)&vh[0][bb][4 * j] = p;
    }

    // reducer-thread constants (thread tid<256 owns unit u=tid)
    float bI = 0.f, bF = 0.f, bG = 0.f, bO = 0.f;
    float pi = 0.f, pf = 0.f, po = 0.f, c0 = 0.f, c1 = 0.f;
    if (tid < H_DIM) {
        bI = bsum[l * G4H + tid];
        bF = bsum[l * G4H + 256 + tid];
        bG = bsum[l * G4H + 512 + tid];
        bO = bsum[l * G4H + 768 + tid];
        pi = wci[tid]; pf = wcf[tid]; po = wco[tid];
    }

    // weight base for this thread: slice s, unit u, gate g at [k8*1024 + g*256 + u]
    const H24* Wbase = (const H24*)Wh + (size_t)l * (NK8 * 1024)
                     + (size_t)(K8PS * s) * 1024 + u;

    // preload k8=0 weights (4 gates)
    H24 wcur[4], wnxt[4];
    #pragma unroll
    for (int g = 0; g < 4; ++g) wcur[g] = Wbase[g * 256];

    int cur = 0;
    __syncthreads();

    for (int t = 0; t < T; ++t) {
        float acc[4][2];
        #pragma unroll
        for (int g = 0; g < 4; ++g) { acc[g][0] = 0.f; acc[g][1] = 0.f; }

        const H24* vp0 = (const H24*)&vh[cur][0][80 * s];
        const H24* vp1 = (const H24*)&vh[cur][1][80 * s];

        #pragma unroll
        for (int k = 0; k < K8PS; ++k) {
            // prefetch next k-group's weights (wraps to 0 for next timestep)
            const int nk = (k == K8PS - 1) ? 0 : (k + 1);
            #pragma unroll
            for (int g = 0; g < 4; ++g) wnxt[g] = Wbase[(size_t)nk * 1024 + g * 256];

            H24 v0 = vp0[k];
            H24 v1 = vp1[k];
            #pragma unroll
            for (int g = 0; g < 4; ++g) {
                acc[g][0] = FDOT2(wcur[g].x, v0.x, acc[g][0]);
                acc[g][0] = FDOT2(wcur[g].y, v0.y, acc[g][0]);
                acc[g][0] = FDOT2(wcur[g].z, v0.z, acc[g][0]);
                acc[g][0] = FDOT2(wcur[g].w, v0.w, acc[g][0]);
                acc[g][1] = FDOT2(wcur[g].x, v1.x, acc[g][1]);
                acc[g][1] = FDOT2(wcur[g].y, v1.y, acc[g][1]);
                acc[g][1] = FDOT2(wcur[g].z, v1.z, acc[g][1]);
                acc[g][1] = FDOT2(wcur[g].w, v1.w, acc[g][1]);
            }
            #pragma unroll
            for (int g = 0; g < 4; ++g) wcur[g] = wnxt[g];
        }

        if (s) {
            #pragma unroll
            for (int g = 0; g < 4; ++g) {
                part[s - 1][0][g][u] = acc[g][0];
                part[s - 1][1][g][u] = acc[g][1];
            }
        } else if (s == 0) {
            // nothing: s==0 keeps partials in registers
        }
        // prefetch x_{t+1} (fp32->fp16) into the other buffer's x region
        if (s == 1 && u < 32) {
            int tt = t + 1;
            if (tt < T) {
                int bb = u >> 4, j = u & 15;
                float4 v = *(const float4*)(x + ((size_t)(b0 + bb) * T + tt) * I_DIM + 4 * j);
                H22 p;
                p.x = h2{(_Float16)v.x, (_Float16)v.y};
                p.y = h2{(_Float16)v.z, (_Float16)v.w};
                *(H22*)&vh[cur ^ 1][bb][4 * j] = p;
            }
        }
        __syncthreads();

        if (tid < H_DIM) {
            #pragma unroll
            for (int b = 0; b < 2; ++b) {
                float gi = acc[0][b] + part[0][b][0][u] + part[1][b][0][u] + part[2][b][0][u] + bI;
                float gf = acc[1][b] + part[0][b][1][u] + part[1][b][1][u] + part[2][b][1][u] + bF;
                float gg = acc[2][b] + part[0][b][2][u] + part[1][b][2][u] + part[2][b][2][u] + bG;
                float go = acc[3][b] + part[0][b][3][u] + part[1][b][3][u] + part[2][b][3][u] + bO;
                float c  = b ? c1 : c0;
                float i_ = sigmoidf(gi + pi * c);
                float f_ = sigmoidf(gf + pf * c);
                float g_ = tanh_fast(gg);
                float cy = f_ * c + i_ * g_;
                float o_ = sigmoidf(go + po * cy);
                float hy = o_ * tanh_fast(cy);
                if (b) c1 = cy; else c0 = cy;
                vh[cur ^ 1][b][I_DIM + u] = (_Float16)hy;
                hseq[((size_t)(b0 + b) * ST + toff + t) * H_DIM + u] = hy;
            }
        }
        __syncthreads();
        cur ^= 1;
    }
}

// ---------------------------------------------------------------------------
// fc1 split-K partial GEMM (unchanged)
// ---------------------------------------------------------------------------
__global__ __launch_bounds__(256) void fc1_partial(const float* __restrict__ hseq,
                                                   const float* __restrict__ w,
                                                   float* __restrict__ part) {
    const int s  = blockIdx.x;          // 0..NSLICE-1
    const int k0 = s * KC;
    const int kend = (k0 + KC < F1) ? (k0 + KC) : F1;

    __shared__ float As[KCH][129];      // As[k][b]
    __shared__ float Bs[KCH][129];      // Bs[k][j]

    const int tid = threadIdx.x;
    const int tx = tid & 15;            // j block
    const int ty = tid >> 4;            // b block

    float acc[8][8];
    #pragma unroll
    for (int i = 0; i < 8; ++i)
        #pragma unroll
        for (int j = 0; j < 8; ++j) acc[i][j] = 0.f;

    for (int kk = k0; kk < kend; kk += KCH) {
        #pragma unroll
        for (int r = 0; r < 16; ++r) {
            int idx = r * 256 + tid;    // 0..4095
            int row = idx >> 5;
            int k   = idx & 31;
            int gk  = kk + k;
            float av = (gk < F1) ? hseq[(size_t)row * F1 + gk] : 0.f;
            float bv = (gk < F1) ? w[(size_t)row * F1 + gk] : 0.f;
            As[k][row] = av;
            Bs[k][row] = bv;
        }
        __syncthreads();

        #pragma unroll 8
        for (int k = 0; k < KCH; ++k) {
            float av[8], bv[8];
            #pragma unroll
            for (int i = 0; i < 8; ++i) av[i] = As[k][ty * 8 + i];
            #pragma unroll
            for (int j = 0; j < 8; ++j) bv[j] = Bs[k][tx * 8 + j];
            #pragma unroll
            for (int i = 0; i < 8; ++i)
                #pragma unroll
                for (int j = 0; j < 8; ++j)
                    acc[i][j] = fmaf(av[i], bv[j], acc[i][j]);
        }
        __syncthreads();
    }

    float* dst = part + (size_t)s * (BATCH * 128);
    #pragma unroll
    for (int i = 0; i < 8; ++i)
        #pragma unroll
        for (int j = 0; j < 8; ++j)
            dst[(size_t)(ty * 8 + i) * 128 + (tx * 8 + j)] = acc[i][j];
}

__global__ __launch_bounds__(256) void fc1_reduce(const float* __restrict__ part,
                                                  const float* __restrict__ fc1_b,
                                                  float* __restrict__ out1) {
    int flat = blockIdx.x * 256 + threadIdx.x;     // 0..16383
    float sum = 0.f;
    for (int i = 0; i < NSLICE; ++i)
        sum += part[(size_t)i * (BATCH * 128) + flat];
    int j = flat & 127;
    sum += fc1_b[j];
    out1[flat] = fmaxf(sum, 0.f);
}

__global__ __launch_bounds__(128) void fc2_kernel(const float* __restrict__ out1,
                                                  const float* __restrict__ fcw,
                                                  const float* __restrict__ fcb,
                                                  float* __restrict__ out) {
    int b = blockIdx.x;
    __shared__ float ro[128];
    int tid = threadIdx.x;
    ro[tid] = out1[(size_t)b * 128 + tid];
    __syncthreads();
    if (tid < NC) {
        float s = fcb[tid];
        #pragma unroll 8
        for (int j = 0; j < 128; ++j)
            s = fmaf(ro[j], fcw[(size_t)tid * 128 + j], s);
        out[(size_t)b * NC + tid] = s;
    }
}

// ---------------------------------------------------------------------------
extern "C" void kernel_launch(void* const* d_in, const int* in_sizes, int n_in,
                              void* d_out, int out_size, void* d_ws, size_t ws_size,
                              hipStream_t stream) {
    const float* rr_x  = (const float*)d_in[0];
    const float* rr_wv = (const float*)d_in[1];
    const float* w_ih1 = (const float*)d_in[2];
    const float* w_hh1 = (const float*)d_in[3];
    const float* b_ih1 = (const float*)d_in[4];
    const float* b_hh1 = (const float*)d_in[5];
    const float* wci1  = (const float*)d_in[6];
    const float* wcf1  = (const float*)d_in[7];
    const float* wco1  = (const float*)d_in[8];
    const float* w_ih2 = (const float*)d_in[9];
    const float* w_hh2 = (const float*)d_in[10];
    const float* b_ih2 = (const float*)d_in[11];
    const float* b_hh2 = (const float*)d_in[12];
    const float* wci2  = (const float*)d_in[13];
    const float* wcf2  = (const float*)d_in[14];
    const float* wco2  = (const float*)d_in[15];
    const float* fc1_w = (const float*)d_in[16];
    const float* fc1_b = (const float*)d_in[17];
    const float* fc_w  = (const float*)d_in[18];
    const float* fc_b  = (const float*)d_in[19];
    float* out = (float*)d_out;

    char* ws = (char*)d_ws;
    size_t off = 0;
    _Float16* Wh  = (_Float16*)(ws + off); off += (size_t)2 * NK8 * 1024 * 8 * sizeof(_Float16); // 1.31MB
    float* bsum = (float*)(ws + off);  off += (size_t)2 * G4H * sizeof(float);
    float* hseq = (float*)(ws + off);  off += (size_t)BATCH * F1 * sizeof(float);
    float* part = (float*)(ws + off);  off += (size_t)NSLICE * BATCH * 128 * sizeof(float);
    float* out1 = (float*)(ws + off);  off += (size_t)BATCH * 128 * sizeof(float);

    prep_pack<<<8, 256, 0, stream>>>(w_ih1, w_hh1, b_ih1, b_hh1,
                                     w_ih2, w_hh2, b_ih2, b_hh2, Wh, bsum);

    lstm_fused<<<128, 1024, 0, stream>>>(rr_x, rr_wv,
                                         wci1, wcf1, wco1, wci2, wcf2, wco2,
                                         Wh, bsum, hseq);

    fc1_partial<<<NSLICE, 256, 0, stream>>>(hseq, fc1_w, part);
    fc1_reduce<<<BATCH * 128 / 256, 256, 0, stream>>>(part, fc1_b, out1);
    fc2_kernel<<<BATCH, 128, 0, stream>>>(out1, fc_w, fc_b, out);
}

// Round 6
// 6427.347 us; speedup vs baseline: 2.5984x; 1.2543x over previous
//
#include <hip/hip_runtime.h>
#include <hip/hip_bf16.h>
#include <hip/hip_fp16.h>
#include <math.h>

// Problem constants
#define I_DIM 64
#define H_DIM 256
#define NC    10
#define S1    500
#define S2    41
#define BATCH 128
#define ST    (S1 + S2)          // 541
#define F1    (ST * H_DIM)       // 138496
#define KTOT  (I_DIM + H_DIM)    // 320
#define NKK   10                 // K-steps of 32
#define MB    16                 // batch rows per block
#define VH_STRIDE 328            // fp16 row stride for [x|h] (320 + 8 pad)

// fc1 split-K params
#define KC   512
#define KCH  32
#define NSLICE ((F1 + KC - 1) / KC)   // 271

typedef _Float16 f16x8 __attribute__((ext_vector_type(8)));
typedef _Float16 f16x4 __attribute__((ext_vector_type(4)));
typedef float    f32x4 __attribute__((ext_vector_type(4)));

__device__ __forceinline__ float sigmoidf(float x) {
    return 1.0f / (1.0f + __expf(-x));
}
__device__ __forceinline__ float tanh_fast(float x) {
    float e = __expf(2.0f * x);
    return 1.0f - 2.0f / (e + 1.0f);
}

// ---------------------------------------------------------------------------
// Pack [w_ih | w_hh] (fp32) into MFMA B-fragment order, fp16:
//   Bp[ ((l*NKK + kk)*64 + ntg)*64 + lane ]  (one f16x8 per lane)
//   n = ntg*16 + (lane&15);  k = kk*32 + (lane>>4)*8 + e
//   value = k < 64 ? w_ih[n][k] : w_hh[n][k-64]
// A-frags are read from LDS with the SAME (lane,e)->k map, so the contraction
// is correct independent of the HW's internal k-order (bijection invariance).
// ---------------------------------------------------------------------------
__global__ __launch_bounds__(256) void prep_pack_b(
        const float* __restrict__ wih1, const float* __restrict__ whh1,
        const float* __restrict__ wih2, const float* __restrict__ whh2,
        f16x8* __restrict__ Bp) {
    int gid = blockIdx.x * 256 + threadIdx.x;      // 0..81919
    int lane = gid & 63;
    int frag = gid >> 6;                           // 0..1279
    int ntg  = frag & 63;
    int rest = frag >> 6;                          // 0..19
    int kk   = rest % NKK;
    int l    = rest / NKK;
    const float* wih = l ? wih2 : wih1;
    const float* whh = l ? whh2 : whh1;
    int n  = ntg * 16 + (lane & 15);               // gate row 0..1023
    int k0 = kk * 32 + (lane >> 4) * 8;
    f16x8 v;
    #pragma unroll
    for (int e = 0; e < 8; ++e) {
        int k = k0 + e;
        float f = (k < I_DIM) ? wih[(size_t)n * I_DIM + k]
                              : whh[(size_t)n * H_DIM + (k - I_DIM)];
        v[e] = (_Float16)f;
    }
    Bp[gid] = v;
}

__global__ __launch_bounds__(256) void prep_bias(
        const float* __restrict__ bih1, const float* __restrict__ bhh1,
        const float* __restrict__ bih2, const float* __restrict__ bhh2,
        float* __restrict__ bsum) {
    int gid = blockIdx.x * 256 + threadIdx.x;      // 0..2047
    if (gid >= 2048) return;
    int l = gid >> 10, n = gid & 1023;
    bsum[gid] = l ? (bih2[n] + bhh2[n]) : (bih1[n] + bhh1[n]);
}

// ---------------------------------------------------------------------------
// MFMA peephole LSTM, in-lane activation, partial B residency.
// Grid: 16 blocks x 1024 threads (16 waves). Block = (l = blk>>3, 16-batch).
// Wave w owns n-tiles {w, 16+w, 32+w, 48+w} = gates i,f,c,o for units
// [16w,16w+16): each lane ends the GEMM holding ALL 4 gates of its 4 cells
// (batch rows (lane>>4)*4+r) in acc[q][r] -> activation entirely in-lane,
// c-state in registers, ONE barrier per step.
// B: kk=0,1 in registers (persistent), kk=8,9 in LDS (persistent, 131 KB),
// kk=2..7 streamed from L2 via a depth-2 ring (6 % 2 == 0 -> periodic:
// preload kk2,kk3; at kk=6,7 reload kk2,kk3 for the next step).
// ---------------------------------------------------------------------------
__global__ __launch_bounds__(1024) void lstm_mfma(
        const float* __restrict__ x1, const float* __restrict__ x2,
        const float* __restrict__ wci1, const float* __restrict__ wcf1, const float* __restrict__ wco1,
        const float* __restrict__ wci2, const float* __restrict__ wcf2, const float* __restrict__ wco2,
        const f16x8* __restrict__ Bp, const float* __restrict__ bsum,
        float* __restrict__ hseq) {
    const int blk = blockIdx.x;            // 0..15
    const int l   = blk >> 3;
    const int b0  = (blk & 7) * MB;
    const int T    = l ? S2 : S1;
    const int toff = l ? S1 : 0;
    const float* x   = l ? x2 : x1;
    const float* wci = l ? wci2 : wci1;
    const float* wcf = l ? wcf2 : wcf1;
    const float* wco = l ? wco2 : wco1;

    const int tid  = threadIdx.x;
    const int lane = tid & 63;
    const int wv   = tid >> 6;             // wave 0..15
    const int lr   = lane & 15;            // A-row / n-in-tile
    const int lg   = lane >> 4;            // k-group / batch-quad

    __shared__ __align__(16) _Float16 vh[2][MB][VH_STRIDE];  // [x|h] fp16, dbuf
    __shared__ f16x8 Bl[2 * 64 * 64];                        // kk=8,9 fragments

    // zero vh (h region of buf0 must be 0 at t=0)
    for (int i = tid; i < (int)(sizeof(vh) / 4); i += 1024) ((int*)vh)[i] = 0;
    __syncthreads();   // before x_0 staging overwrites part of it

    // stage x_0 (fp32 -> fp16)
    if (tid < 256) {
        int bb = tid >> 4, k4 = tid & 15;
        float4 v = *(const float4*)(x + ((size_t)(b0 + bb) * T + 0) * I_DIM + 4 * k4);
        f16x4 p = { (_Float16)v.x, (_Float16)v.y, (_Float16)v.z, (_Float16)v.w };
        *(f16x4*)&vh[0][bb][4 * k4] = p;
    }
    // stage kk=8,9 B fragments into LDS (one-time, coalesced)
    {
        const f16x8* BPl = Bp + ((size_t)l * NKK + 8) * 4096;
        #pragma unroll
        for (int i = 0; i < 8; ++i) Bl[tid + i * 1024] = BPl[tid + i * 1024];
    }

    // per-lane constants: unit u, biases, peephole weights, c-state
    const int u = wv * 16 + lr;
    float biasv[4];
    #pragma unroll
    for (int q = 0; q < 4; ++q) biasv[q] = bsum[l * 1024 + q * 256 + u];
    const float pi = wci[u], pf = wcf[u], po = wco[u];
    float cst[4] = {0.f, 0.f, 0.f, 0.f};

    // B fragment (kk, gate q) for this wave
    #define BFRAG(kk, q) Bp[(((size_t)l * NKK + (kk)) * 64 + (q) * 16 + wv) * 64 + lane]

    f16x8 breg[2][4], sbuf[2][4];
    #pragma unroll
    for (int q = 0; q < 4; ++q) {
        breg[0][q] = BFRAG(0, q);
        breg[1][q] = BFRAG(1, q);
        sbuf[0][q] = BFRAG(2, q);
        sbuf[1][q] = BFRAG(3, q);
    }

    int cur = 0;
    __syncthreads();

    for (int t = 0; t < T; ++t) {
        f32x4 acc[4];
        #pragma unroll
        for (int q = 0; q < 4; ++q)
            acc[q] = (f32x4){biasv[q], biasv[q], biasv[q], biasv[q]};

        const _Float16* vrow = &vh[cur][lr][lg * 8];

        // kk = 0,1 : register-resident (x-part weights)
        #pragma unroll
        for (int kk = 0; kk < 2; ++kk) {
            f16x8 a = *(const f16x8*)(vrow + kk * 32);
            #pragma unroll
            for (int q = 0; q < 4; ++q)
                acc[q] = __builtin_amdgcn_mfma_f32_16x16x32_f16(a, breg[kk][q], acc[q], 0, 0, 0);
        }
        // kk = 8,9 : LDS-resident
        #pragma unroll
        for (int kb = 0; kb < 2; ++kb) {
            f16x8 a = *(const f16x8*)(vrow + (8 + kb) * 32);
            #pragma unroll
            for (int q = 0; q < 4; ++q) {
                f16x8 b = Bl[((kb * 64) + q * 16 + wv) * 64 + lane];
                acc[q] = __builtin_amdgcn_mfma_f32_16x16x32_f16(a, b, acc[q], 0, 0, 0);
            }
        }
        // kk = 2..7 : streamed, depth-2 ring (periodic since 6 % 2 == 0)
        #pragma unroll
        for (int kk = 2; kk <= 7; ++kk) {
            f16x8 a = *(const f16x8*)(vrow + kk * 32);
            const int slot = kk & 1;
            #pragma unroll
            for (int q = 0; q < 4; ++q)
                acc[q] = __builtin_amdgcn_mfma_f32_16x16x32_f16(a, sbuf[slot][q], acc[q], 0, 0, 0);
            const int nk = (kk + 2 > 7) ? (kk - 4) : (kk + 2);   // 6->2, 7->3 (next step)
            #pragma unroll
            for (int q = 0; q < 4; ++q)
                sbuf[slot][q] = BFRAG(nk, q);
        }

        // in-lane activation: 4 cells (batch lg*4+r, unit u)
        #pragma unroll
        for (int r = 0; r < 4; ++r) {
            int b = lg * 4 + r;
            float c  = cst[r];
            float i_ = sigmoidf(acc[0][r] + pi * c);
            float f_ = sigmoidf(acc[1][r] + pf * c);
            float g_ = tanh_fast(acc[2][r]);
            float cy = f_ * c + i_ * g_;
            float o_ = sigmoidf(acc[3][r] + po * cy);
            float hy = o_ * tanh_fast(cy);
            cst[r] = cy;
            vh[cur ^ 1][b][I_DIM + u] = (_Float16)hy;
            hseq[((size_t)(b0 + b) * ST + toff + t) * H_DIM + u] = hy;
        }
        // stage x_{t+1} into the other buffer
        if (tid < 256 && t + 1 < T) {
            int bb = tid >> 4, k4 = tid & 15;
            float4 v = *(const float4*)(x + ((size_t)(b0 + bb) * T + (t + 1)) * I_DIM + 4 * k4);
            f16x4 p = { (_Float16)v.x, (_Float16)v.y, (_Float16)v.z, (_Float16)v.w };
            *(f16x4*)&vh[cur ^ 1][bb][4 * k4] = p;
        }
        __syncthreads();
        cur ^= 1;
    }
    #undef BFRAG
}

// ---------------------------------------------------------------------------
// fc1 split-K partial GEMM (unchanged)
// ---------------------------------------------------------------------------
__global__ __launch_bounds__(256) void fc1_partial(const float* __restrict__ hseq,
                                                   const float* __restrict__ w,
                                                   float* __restrict__ part) {
    const int s  = blockIdx.x;          // 0..NSLICE-1
    const int k0 = s * KC;
    const int kend = (k0 + KC < F1) ? (k0 + KC) : F1;

    __shared__ float As[KCH][129];      // As[k][b]
    __shared__ float Bs[KCH][129];      // Bs[k][j]

    const int tid = threadIdx.x;
    const int tx = tid & 15;            // j block
    const int ty = tid >> 4;            // b block

    float acc[8][8];
    #pragma unroll
    for (int i = 0; i < 8; ++i)
        #pragma unroll
        for (int j = 0; j < 8; ++j) acc[i][j] = 0.f;

    for (int kk = k0; kk < kend; kk += KCH) {
        #pragma unroll
        for (int r = 0; r < 16; ++r) {
            int idx = r * 256 + tid;    // 0..4095
            int row = idx >> 5;
            int k   = idx & 31;
            int gk  = kk + k;
            float av = (gk < F1) ? hseq[(size_t)row * F1 + gk] : 0.f;
            float bv = (gk < F1) ? w[(size_t)row * F1 + gk] : 0.f;
            As[k][row] = av;
            Bs[k][row] = bv;
        }
        __syncthreads();

        #pragma unroll 8
        for (int k = 0; k < KCH; ++k) {
            float av[8], bv[8];
            #pragma unroll
            for (int i = 0; i < 8; ++i) av[i] = As[k][ty * 8 + i];
            #pragma unroll
            for (int j = 0; j < 8; ++j) bv[j] = Bs[k][tx * 8 + j];
            #pragma unroll
            for (int i = 0; i < 8; ++i)
                #pragma unroll
                for (int j = 0; j < 8; ++j)
                    acc[i][j] = fmaf(av[i], bv[j], acc[i][j]);
        }
        __syncthreads();
    }

    float* dst = part + (size_t)s * (BATCH * 128);
    #pragma unroll
    for (int i = 0; i < 8; ++i)
        #pragma unroll
        for (int j = 0; j < 8; ++j)
            dst[(size_t)(ty * 8 + i) * 128 + (tx * 8 + j)] = acc[i][j];
}

__global__ __launch_bounds__(256) void fc1_reduce(const float* __restrict__ part,
                                                  const float* __restrict__ fc1_b,
                                                  float* __restrict__ out1) {
    int flat = blockIdx.x * 256 + threadIdx.x;     // 0..16383
    float sum = 0.f;
    for (int i = 0; i < NSLICE; ++i)
        sum += part[(size_t)i * (BATCH * 128) + flat];
    int j = flat & 127;
    sum += fc1_b[j];
    out1[flat] = fmaxf(sum, 0.f);
}

__global__ __launch_bounds__(128) void fc2_kernel(const float* __restrict__ out1,
                                                  const float* __restrict__ fcw,
                                                  const float* __restrict__ fcb,
                                                  float* __restrict__ out) {
    int b = blockIdx.x;
    __shared__ float ro[128];
    int tid = threadIdx.x;
    ro[tid] = out1[(size_t)b * 128 + tid];
    __syncthreads();
    if (tid < NC) {
        float s = fcb[tid];
        #pragma unroll 8
        for (int j = 0; j < 128; ++j)
            s = fmaf(ro[j], fcw[(size_t)tid * 128 + j], s);
        out[(size_t)b * NC + tid] = s;
    }
}

// ---------------------------------------------------------------------------
extern "C" void kernel_launch(void* const* d_in, const int* in_sizes, int n_in,
                              void* d_out, int out_size, void* d_ws, size_t ws_size,
                              hipStream_t stream) {
    const float* rr_x  = (const float*)d_in[0];
    const float* rr_wv = (const float*)d_in[1];
    const float* w_ih1 = (const float*)d_in[2];
    const float* w_hh1 = (const float*)d_in[3];
    const float* b_ih1 = (const float*)d_in[4];
    const float* b_hh1 = (const float*)d_in[5];
    const float* wci1  = (const float*)d_in[6];
    const float* wcf1  = (const float*)d_in[7];
    const float* wco1  = (const float*)d_in[8];
    const float* w_ih2 = (const float*)d_in[9];
    const float* w_hh2 = (const float*)d_in[10];
    const float* b_ih2 = (const float*)d_in[11];
    const float* b_hh2 = (const float*)d_in[12];
    const float* wci2  = (const float*)d_in[13];
    const float* wcf2  = (const float*)d_in[14];
    const float* wco2  = (const float*)d_in[15];
    const float* fc1_w = (const float*)d_in[16];
    const float* fc1_b = (const float*)d_in[17];
    const float* fc_w  = (const float*)d_in[18];
    const float* fc_b  = (const float*)d_in[19];
    float* out = (float*)d_out;

    char* ws = (char*)d_ws;
    size_t off = 0;
    f16x8* Bp  = (f16x8*)(ws + off);  off += (size_t)2 * NKK * 64 * 64 * sizeof(f16x8); // 1.31 MB
    float* bsum = (float*)(ws + off); off += (size_t)2048 * sizeof(float);
    float* hseq = (float*)(ws + off); off += (size_t)BATCH * F1 * sizeof(float);        // 70.9 MB
    float* part = (float*)(ws + off); off += (size_t)NSLICE * BATCH * 128 * sizeof(float);
    float* out1 = (float*)(ws + off); off += (size_t)BATCH * 128 * sizeof(float);

    prep_pack_b<<<320, 256, 0, stream>>>(w_ih1, w_hh1, w_ih2, w_hh2, Bp);
    prep_bias<<<8, 256, 0, stream>>>(b_ih1, b_hh1, b_ih2, b_hh2, bsum);

    lstm_mfma<<<16, 1024, 0, stream>>>(rr_x, rr_wv,
                                       wci1, wcf1, wco1, wci2, wcf2, wco2,
                                       Bp, bsum, hseq);

    fc1_partial<<<NSLICE, 256, 0, stream>>>(hseq, fc1_w, part);
    fc1_reduce<<<BATCH * 128 / 256, 256, 0, stream>>>(part, fc1_b, out1);
    fc2_kernel<<<BATCH, 128, 0, stream>>>(out1, fc_w, fc_b, out);
}

// Round 7
// 3065.252 us; speedup vs baseline: 5.4483x; 2.0968x over previous
//
#include <hip/hip_runtime.h>
#include <hip/hip_bf16.h>
#include <hip/hip_fp16.h>
#include <math.h>

// Problem constants
#define I_DIM 64
#define H_DIM 256
#define NC    10
#define S1    500
#define S2    41
#define BATCH 128
#define ST    (S1 + S2)          // 541
#define F1    (ST * H_DIM)       // 138496
#define KTOT  (I_DIM + H_DIM)    // 320
#define NKK   10                 // K-steps of 32
#define MB    16                 // batch rows per chunk
#define VH_STRIDE 328            // fp16 row stride for [x|h] (320 + 8 pad)

// fc1 split-K params
#define KC   512
#define KCH  32
#define NSLICE ((F1 + KC - 1) / KC)   // 271

typedef _Float16 f16x8 __attribute__((ext_vector_type(8)));
typedef _Float16 f16x4 __attribute__((ext_vector_type(4)));
typedef float    f32x4 __attribute__((ext_vector_type(4)));

__device__ __forceinline__ float sigmoidf(float x) {
    return 1.0f / (1.0f + __expf(-x));
}
__device__ __forceinline__ float tanh_fast(float x) {
    float e = __expf(2.0f * x);
    return 1.0f - 2.0f / (e + 1.0f);
}

// ---------------------------------------------------------------------------
// Pack [w_ih | w_hh] (fp32) into MFMA B-fragment order, fp16 (same as r6):
//   Bp[ ((l*NKK + kk)*64 + ntg)*64 + lane ]  (one f16x8 per lane)
//   n = ntg*16 + (lane&15);  k = kk*32 + (lane>>4)*8 + e
// ---------------------------------------------------------------------------
__global__ __launch_bounds__(256) void prep_pack_b(
        const float* __restrict__ wih1, const float* __restrict__ whh1,
        const float* __restrict__ wih2, const float* __restrict__ whh2,
        f16x8* __restrict__ Bp) {
    int gid = blockIdx.x * 256 + threadIdx.x;      // 0..81919
    int lane = gid & 63;
    int frag = gid >> 6;                           // 0..1279
    int ntg  = frag & 63;
    int rest = frag >> 6;                          // 0..19
    int kk   = rest % NKK;
    int l    = rest / NKK;
    const float* wih = l ? wih2 : wih1;
    const float* whh = l ? whh2 : whh1;
    int n  = ntg * 16 + (lane & 15);               // gate row 0..1023
    int k0 = kk * 32 + (lane >> 4) * 8;
    f16x8 v;
    #pragma unroll
    for (int e = 0; e < 8; ++e) {
        int k = k0 + e;
        float f = (k < I_DIM) ? wih[(size_t)n * I_DIM + k]
                              : whh[(size_t)n * H_DIM + (k - I_DIM)];
        v[e] = (_Float16)f;
    }
    Bp[gid] = v;
}

__global__ __launch_bounds__(256) void prep_bias(
        const float* __restrict__ bih1, const float* __restrict__ bhh1,
        const float* __restrict__ bih2, const float* __restrict__ bhh2,
        float* __restrict__ bsum) {
    int gid = blockIdx.x * 256 + threadIdx.x;      // 0..2047
    if (gid >= 2048) return;
    int l = gid >> 10, n = gid & 1023;
    bsum[gid] = l ? (bih2[n] + bhh2[n]) : (bih1[n] + bhh1[n]);
}

// ---------------------------------------------------------------------------
// Pair-split MFMA peephole LSTM with fully register-resident weights.
// Grid: 32 blocks x 512 threads (8 waves, <=256 VGPR, 1 block/CU).
//   bid: xcd = bid&7, HALF = (bid>>3)&1, chunk = (bid>>4)*8 + xcd.
//   chunk: l = chunk>>3 (LSTM1/2), b0 = (chunk&7)*16. Partner = bid^8 (same XCD).
// Block owns units [128*HALF, 128*HALF+128) x 4 gates = 512 of 1024 columns:
// B-half = 40 f16x8 frags/lane = 160 VGPR, loaded ONCE. Per step per wave:
// 40 mfma_16x16x32_f16 (4 n-tiles x 10 kk). Partner h-half exchanged via hseq
// with agent-scope atomics + release/acquire flags (correct cross-XCD).
// Phase A (x + own-half kk) runs before the partner poll to hide latency.
// ---------------------------------------------------------------------------
template<int HALF>
__device__ __forceinline__ void lstm_body(
        int l, int b0, int T, int toff, int chunk,
        const float* __restrict__ x,
        const float* __restrict__ wci, const float* __restrict__ wcf, const float* __restrict__ wco,
        const f16x8* __restrict__ Bp, const float* __restrict__ bsum,
        float* __restrict__ hseq, int* __restrict__ flags,
        _Float16 (*vh)[MB][VH_STRIDE]) {
    const int tid  = threadIdx.x;
    const int lane = tid & 63;
    const int wv   = tid >> 6;             // wave 0..7
    const int lr   = lane & 15;            // n-in-tile / batch row for A
    const int lg   = lane >> 4;            // k-group / batch-quad
    const int uw   = 8 * HALF + wv;        // global unit-tile 0..15
    const int u    = uw * 16 + lr;         // global unit 0..255

    // zero vh (h of buf0 must be 0 at t=0; partner region starts as 0)
    for (int i = tid; i < 2 * MB * VH_STRIDE / 2; i += 512) ((int*)vh)[i] = 0;
    __syncthreads();
    // stage x_0 (fp32 -> fp16)
    if (tid < 256) {
        int bb = tid >> 4, k4 = tid & 15;
        float4 v = *(const float4*)(x + ((size_t)(b0 + bb) * T + 0) * I_DIM + 4 * k4);
        f16x4 p = { (_Float16)v.x, (_Float16)v.y, (_Float16)v.z, (_Float16)v.w };
        *(f16x4*)&vh[0][bb][4 * k4] = p;
    }

    // one-time: this block's B-half into registers (40 frags = 160 VGPR)
    f16x8 wreg[NKK][4];
    #pragma unroll
    for (int kk = 0; kk < NKK; ++kk)
        #pragma unroll
        for (int q = 0; q < 4; ++q)
            wreg[kk][q] = Bp[(((size_t)l * NKK + kk) * 64 + q * 16 + uw) * 64 + lane];

    float biasv[4];
    #pragma unroll
    for (int q = 0; q < 4; ++q) biasv[q] = bsum[l * 1024 + q * 256 + u];
    const float pi = wci[u], pf = wcf[u], po = wco[u];
    float cst[4] = {0.f, 0.f, 0.f, 0.f};

    const int myflag = chunk * 2 + HALF;
    const int pflag  = chunk * 2 + (1 - HALF);
    // partner-read mapping: thread covers (batch pb, 4 units at pu)
    const int pb  = tid >> 5;              // 0..15
    const int pu  = 128 * (1 - HALF) + (tid & 31) * 4;

    int cur = 0;
    __syncthreads();

    for (int t = 0; t < T; ++t) {
        // issue x_{t+1} load early (committed at end of step)
        float4 xn = make_float4(0.f, 0.f, 0.f, 0.f);
        const bool havex = (tid < 256) && (t + 1 < T);
        if (havex)
            xn = *(const float4*)(x + ((size_t)(b0 + (tid >> 4)) * T + (t + 1)) * I_DIM + 4 * (tid & 15));

        f32x4 acc[4];
        #pragma unroll
        for (int q = 0; q < 4; ++q)
            acc[q] = (f32x4){biasv[q], biasv[q], biasv[q], biasv[q]};

#define MK(kk) do {                                                                     \
        f16x8 a_ = *(const f16x8*)&vh[cur][lr][(kk) * 32 + lg * 8];                     \
        acc[0] = __builtin_amdgcn_mfma_f32_16x16x32_f16(a_, wreg[kk][0], acc[0], 0,0,0);\
        acc[1] = __builtin_amdgcn_mfma_f32_16x16x32_f16(a_, wreg[kk][1], acc[1], 0,0,0);\
        acc[2] = __builtin_amdgcn_mfma_f32_16x16x32_f16(a_, wreg[kk][2], acc[2], 0,0,0);\
        acc[3] = __builtin_amdgcn_mfma_f32_16x16x32_f16(a_, wreg[kk][3], acc[3], 0,0,0);\
    } while (0)

        // PHASE A: x part + own h-half (valid in vh[cur] at entry)
        MK(0); MK(1);
        if constexpr (HALF == 0) { MK(2); MK(3); MK(4); MK(5); }
        else                     { MK(6); MK(7); MK(8); MK(9); }

        // exchange: pull partner h_{t-1} (skip t=0: zeros already staged)
        if (t > 0) {
            while (__hip_atomic_load(&flags[pflag], __ATOMIC_ACQUIRE,
                                     __HIP_MEMORY_SCOPE_AGENT) < t)
                __builtin_amdgcn_s_sleep(2);
            float* pr = (float*)&hseq[((size_t)(b0 + pb) * ST + toff + (t - 1)) * H_DIM + pu];
            float v0 = __hip_atomic_load(pr + 0, __ATOMIC_RELAXED, __HIP_MEMORY_SCOPE_AGENT);
            float v1 = __hip_atomic_load(pr + 1, __ATOMIC_RELAXED, __HIP_MEMORY_SCOPE_AGENT);
            float v2 = __hip_atomic_load(pr + 2, __ATOMIC_RELAXED, __HIP_MEMORY_SCOPE_AGENT);
            float v3 = __hip_atomic_load(pr + 3, __ATOMIC_RELAXED, __HIP_MEMORY_SCOPE_AGENT);
            f16x4 ph = { (_Float16)v0, (_Float16)v1, (_Float16)v2, (_Float16)v3 };
            *(f16x4*)&vh[cur][pb][I_DIM + pu] = ph;
        }
        __syncthreads();   // partner region of vh[cur] now valid

        // PHASE B: partner h-half
        if constexpr (HALF == 0) { MK(6); MK(7); MK(8); MK(9); }
        else                     { MK(2); MK(3); MK(4); MK(5); }
#undef MK

        // in-lane activation: 4 cells (batch lg*4+r, unit u)
        #pragma unroll
        for (int r = 0; r < 4; ++r) {
            int b = lg * 4 + r;
            float c  = cst[r];
            float i_ = sigmoidf(acc[0][r] + pi * c);
            float f_ = sigmoidf(acc[1][r] + pf * c);
            float g_ = tanh_fast(acc[2][r]);
            float cy = f_ * c + i_ * g_;
            float o_ = sigmoidf(acc[3][r] + po * cy);
            float hy = o_ * tanh_fast(cy);
            cst[r] = cy;
            vh[cur ^ 1][b][I_DIM + u] = (_Float16)hy;
            __hip_atomic_store(&hseq[((size_t)(b0 + b) * ST + toff + t) * H_DIM + u], hy,
                               __ATOMIC_RELAXED, __HIP_MEMORY_SCOPE_AGENT);
        }
        // commit x_{t+1}
        if (havex) {
            f16x4 p = { (_Float16)xn.x, (_Float16)xn.y, (_Float16)xn.z, (_Float16)xn.w };
            *(f16x4*)&vh[cur ^ 1][tid >> 4][4 * (tid & 15)] = p;
        }
        __threadfence();   // own h stores globally visible
        __syncthreads();   // vh[cur^1] own+x complete; all threads' stores fenced
        if (tid == 0)
            __hip_atomic_store(&flags[myflag], t + 1, __ATOMIC_RELEASE,
                               __HIP_MEMORY_SCOPE_AGENT);
        cur ^= 1;
    }
}

__global__ __launch_bounds__(512, 2) void lstm_pair(
        const float* __restrict__ x1, const float* __restrict__ x2,
        const float* __restrict__ wci1, const float* __restrict__ wcf1, const float* __restrict__ wco1,
        const float* __restrict__ wci2, const float* __restrict__ wcf2, const float* __restrict__ wco2,
        const f16x8* __restrict__ Bp, const float* __restrict__ bsum,
        float* __restrict__ hseq, int* __restrict__ flags) {
    __shared__ __align__(16) _Float16 vh[2][MB][VH_STRIDE];
    const int bid  = blockIdx.x;           // 0..31
    const int xcd  = bid & 7;
    const int half = (bid >> 3) & 1;
    const int chunk = (bid >> 4) * 8 + xcd;    // 0..15
    const int l    = chunk >> 3;
    const int b0   = (chunk & 7) * MB;
    const int T    = l ? S2 : S1;
    const int toff = l ? S1 : 0;
    const float* x   = l ? x2 : x1;
    const float* wci = l ? wci2 : wci1;
    const float* wcf = l ? wcf2 : wcf1;
    const float* wco = l ? wco2 : wco1;
    if (half == 0)
        lstm_body<0>(l, b0, T, toff, chunk, x, wci, wcf, wco, Bp, bsum, hseq, flags, vh);
    else
        lstm_body<1>(l, b0, T, toff, chunk, x, wci, wcf, wco, Bp, bsum, hseq, flags, vh);
}

// ---------------------------------------------------------------------------
// fc1 split-K partial GEMM (unchanged)
// ---------------------------------------------------------------------------
__global__ __launch_bounds__(256) void fc1_partial(const float* __restrict__ hseq,
                                                   const float* __restrict__ w,
                                                   float* __restrict__ part) {
    const int s  = blockIdx.x;          // 0..NSLICE-1
    const int k0 = s * KC;
    const int kend = (k0 + KC < F1) ? (k0 + KC) : F1;

    __shared__ float As[KCH][129];      // As[k][b]
    __shared__ float Bs[KCH][129];      // Bs[k][j]

    const int tid = threadIdx.x;
    const int tx = tid & 15;            // j block
    const int ty = tid >> 4;            // b block

    float acc[8][8];
    #pragma unroll
    for (int i = 0; i < 8; ++i)
        #pragma unroll
        for (int j = 0; j < 8; ++j) acc[i][j] = 0.f;

    for (int kk = k0; kk < kend; kk += KCH) {
        #pragma unroll
        for (int r = 0; r < 16; ++r) {
            int idx = r * 256 + tid;    // 0..4095
            int row = idx >> 5;
            int k   = idx & 31;
            int gk  = kk + k;
            float av = (gk < F1) ? hseq[(size_t)row * F1 + gk] : 0.f;
            float bv = (gk < F1) ? w[(size_t)row * F1 + gk] : 0.f;
            As[k][row] = av;
            Bs[k][row] = bv;
        }
        __syncthreads();

        #pragma unroll 8
        for (int k = 0; k < KCH; ++k) {
            float av[8], bv[8];
            #pragma unroll
            for (int i = 0; i < 8; ++i) av[i] = As[k][ty * 8 + i];
            #pragma unroll
            for (int j = 0; j < 8; ++j) bv[j] = Bs[k][tx * 8 + j];
            #pragma unroll
            for (int i = 0; i < 8; ++i)
                #pragma unroll
                for (int j = 0; j < 8; ++j)
                    acc[i][j] = fmaf(av[i], bv[j], acc[i][j]);
        }
        __syncthreads();
    }

    float* dst = part + (size_t)s * (BATCH * 128);
    #pragma unroll
    for (int i = 0; i < 8; ++i)
        #pragma unroll
        for (int j = 0; j < 8; ++j)
            dst[(size_t)(ty * 8 + i) * 128 + (tx * 8 + j)] = acc[i][j];
}

__global__ __launch_bounds__(256) void fc1_reduce(const float* __restrict__ part,
                                                  const float* __restrict__ fc1_b,
                                                  float* __restrict__ out1) {
    int flat = blockIdx.x * 256 + threadIdx.x;     // 0..16383
    float sum = 0.f;
    for (int i = 0; i < NSLICE; ++i)
        sum += part[(size_t)i * (BATCH * 128) + flat];
    int j = flat & 127;
    sum += fc1_b[j];
    out1[flat] = fmaxf(sum, 0.f);
}

__global__ __launch_bounds__(128) void fc2_kernel(const float* __restrict__ out1,
                                                  const float* __restrict__ fcw,
                                                  const float* __restrict__ fcb,
                                                  float* __restrict__ out) {
    int b = blockIdx.x;
    __shared__ float ro[128];
    int tid = threadIdx.x;
    ro[tid] = out1[(size_t)b * 128 + tid];
    __syncthreads();
    if (tid < NC) {
        float s = fcb[tid];
        #pragma unroll 8
        for (int j = 0; j < 128; ++j)
            s = fmaf(ro[j], fcw[(size_t)tid * 128 + j], s);
        out[(size_t)b * NC + tid] = s;
    }
}

// ---------------------------------------------------------------------------
extern "C" void kernel_launch(void* const* d_in, const int* in_sizes, int n_in,
                              void* d_out, int out_size, void* d_ws, size_t ws_size,
                              hipStream_t stream) {
    const float* rr_x  = (const float*)d_in[0];
    const float* rr_wv = (const float*)d_in[1];
    const float* w_ih1 = (const float*)d_in[2];
    const float* w_hh1 = (const float*)d_in[3];
    const float* b_ih1 = (const float*)d_in[4];
    const float* b_hh1 = (const float*)d_in[5];
    const float* wci1  = (const float*)d_in[6];
    const float* wcf1  = (const float*)d_in[7];
    const float* wco1  = (const float*)d_in[8];
    const float* w_ih2 = (const float*)d_in[9];
    const float* w_hh2 = (const float*)d_in[10];
    const float* b_ih2 = (const float*)d_in[11];
    const float* b_hh2 = (const float*)d_in[12];
    const float* wci2  = (const float*)d_in[13];
    const float* wcf2  = (const float*)d_in[14];
    const float* wco2  = (const float*)d_in[15];
    const float* fc1_w = (const float*)d_in[16];
    const float* fc1_b = (const float*)d_in[17];
    const float* fc_w  = (const float*)d_in[18];
    const float* fc_b  = (const float*)d_in[19];
    float* out = (float*)d_out;

    char* ws = (char*)d_ws;
    size_t off = 0;
    f16x8* Bp  = (f16x8*)(ws + off);  off += (size_t)2 * NKK * 64 * 64 * sizeof(f16x8); // 1.31 MB
    float* bsum = (float*)(ws + off); off += (size_t)2048 * sizeof(float);
    float* hseq = (float*)(ws + off); off += (size_t)BATCH * F1 * sizeof(float);        // 70.9 MB
    float* part = (float*)(ws + off); off += (size_t)NSLICE * BATCH * 128 * sizeof(float);
    float* out1 = (float*)(ws + off); off += (size_t)BATCH * 128 * sizeof(float);
    int*   flags = (int*)(ws + off);  off += 32 * sizeof(int);

    prep_pack_b<<<320, 256, 0, stream>>>(w_ih1, w_hh1, w_ih2, w_hh2, Bp);
    prep_bias<<<8, 256, 0, stream>>>(b_ih1, b_hh1, b_ih2, b_hh2, bsum);
    hipMemsetAsync(flags, 0, 32 * sizeof(int), stream);

    lstm_pair<<<32, 512, 0, stream>>>(rr_x, rr_wv,
                                      wci1, wcf1, wco1, wci2, wcf2, wco2,
                                      Bp, bsum, hseq, flags);

    fc1_partial<<<NSLICE, 256, 0, stream>>>(hseq, fc1_w, part);
    fc1_reduce<<<BATCH * 128 / 256, 256, 0, stream>>>(part, fc1_b, out1);
    fc2_kernel<<<BATCH, 128, 0, stream>>>(out1, fc_w, fc_b, out);
}

// Round 8
// 1511.847 us; speedup vs baseline: 11.0464x; 2.0275x over previous
//
#include <hip/hip_runtime.h>
#include <hip/hip_bf16.h>
#include <hip/hip_fp16.h>
#include <math.h>
#include <stdint.h>

// Problem constants
#define I_DIM 64
#define H_DIM 256
#define NC    10
#define S1    500
#define S2    41
#define BATCH 128
#define ST    (S1 + S2)          // 541
#define F1    (ST * H_DIM)       // 138496
#define KTOT  (I_DIM + H_DIM)    // 320
#define NKK   10                 // K-steps of 32
#define MB    16                 // batch rows per chunk
#define VH_STRIDE 328            // fp16 row stride for [x|h] (320 + 8 pad)

// fc1 split-K params
#define KC   512
#define KCH  32
#define NSLICE ((F1 + KC - 1) / KC)   // 271

typedef _Float16 f16x8 __attribute__((ext_vector_type(8)));
typedef _Float16 f16x4 __attribute__((ext_vector_type(4)));
typedef float    f32x4 __attribute__((ext_vector_type(4)));

__device__ __forceinline__ float sigmoidf(float x) {
    return 1.0f / (1.0f + __expf(-x));
}
__device__ __forceinline__ float tanh_fast(float x) {
    float e = __expf(2.0f * x);
    return 1.0f - 2.0f / (e + 1.0f);
}

// ---------------------------------------------------------------------------
// Pack [w_ih | w_hh] (fp32) into MFMA B-fragment order, fp16 (same as r6/r7):
//   Bp[ ((l*NKK + kk)*64 + ntg)*64 + lane ]  (one f16x8 per lane)
//   n = ntg*16 + (lane&15);  k = kk*32 + (lane>>4)*8 + e
// ---------------------------------------------------------------------------
__global__ __launch_bounds__(256) void prep_pack_b(
        const float* __restrict__ wih1, const float* __restrict__ whh1,
        const float* __restrict__ wih2, const float* __restrict__ whh2,
        f16x8* __restrict__ Bp) {
    int gid = blockIdx.x * 256 + threadIdx.x;      // 0..81919
    int lane = gid & 63;
    int frag = gid >> 6;                           // 0..1279
    int ntg  = frag & 63;
    int rest = frag >> 6;                          // 0..19
    int kk   = rest % NKK;
    int l    = rest / NKK;
    const float* wih = l ? wih2 : wih1;
    const float* whh = l ? whh2 : whh1;
    int n  = ntg * 16 + (lane & 15);               // gate row 0..1023
    int k0 = kk * 32 + (lane >> 4) * 8;
    f16x8 v;
    #pragma unroll
    for (int e = 0; e < 8; ++e) {
        int k = k0 + e;
        float f = (k < I_DIM) ? wih[(size_t)n * I_DIM + k]
                              : whh[(size_t)n * H_DIM + (k - I_DIM)];
        v[e] = (_Float16)f;
    }
    Bp[gid] = v;
}

__global__ __launch_bounds__(256) void prep_bias(
        const float* __restrict__ bih1, const float* __restrict__ bhh1,
        const float* __restrict__ bih2, const float* __restrict__ bhh2,
        float* __restrict__ bsum) {
    int gid = blockIdx.x * 256 + threadIdx.x;      // 0..2047
    if (gid >= 2048) return;
    int l = gid >> 10, n = gid & 1023;
    bsum[gid] = l ? (bih2[n] + bhh2[n]) : (bih1[n] + bhh1[n]);
}

// ---------------------------------------------------------------------------
// Pair-split MFMA peephole LSTM, register-resident weights, FENCE-FREE
// exchange: each 64-bit word = 2 x fp16 h-values + 16-bit step tag, sent as a
// relaxed agent-scope atomic store; receiver polls until tag==t. The tag and
// data travel in one atomic word -> no release/acquire fences, no threadfence.
// Grid: 32 blocks x 512 threads; pair = (bid, bid^8) (same XCD under
// round-robin dispatch; correctness does not depend on it).
// xbuf slot layout: slot = chunk*2 + senderHALF; word idx = u_local*8 + bp
// (u_local 0..127, bp = batch pair 0..7); payload (h[2bp][u], h[2bp+1][u]).
// ---------------------------------------------------------------------------
template<int HALF>
__device__ __forceinline__ void lstm_body(
        int l, int b0, int T, int toff, int chunk,
        const float* __restrict__ x,
        const float* __restrict__ wci, const float* __restrict__ wcf, const float* __restrict__ wco,
        const f16x8* __restrict__ Bp, const float* __restrict__ bsum,
        float* __restrict__ hseq, unsigned long long* __restrict__ xbuf,
        _Float16 (*vh)[MB][VH_STRIDE]) {
    const int tid  = threadIdx.x;
    const int lane = tid & 63;
    const int wv   = tid >> 6;             // wave 0..7
    const int lr   = lane & 15;            // n-in-tile / batch row for A
    const int lg   = lane >> 4;            // k-group / batch-quad
    const int uw   = 8 * HALF + wv;        // global unit-tile 0..15
    const int u    = uw * 16 + lr;         // global unit 0..255
    const int ul   = 16 * wv + lr;         // unit local to this half 0..127

    // zero vh (h of buf0 must be 0 at t=0; partner region starts as 0)
    for (int i = tid; i < 2 * MB * VH_STRIDE / 2; i += 512) ((int*)vh)[i] = 0;
    __syncthreads();
    // stage x_0 (fp32 -> fp16)
    if (tid < 256) {
        int bb = tid >> 4, k4 = tid & 15;
        float4 v = *(const float4*)(x + ((size_t)(b0 + bb) * T + 0) * I_DIM + 4 * k4);
        f16x4 p = { (_Float16)v.x, (_Float16)v.y, (_Float16)v.z, (_Float16)v.w };
        *(f16x4*)&vh[0][bb][4 * k4] = p;
    }

    // one-time: this block's B-half into registers/AGPRs (40 frags)
    f16x8 wreg[NKK][4];
    #pragma unroll
    for (int kk = 0; kk < NKK; ++kk)
        #pragma unroll
        for (int q = 0; q < 4; ++q)
            wreg[kk][q] = Bp[(((size_t)l * NKK + kk) * 64 + q * 16 + uw) * 64 + lane];

    float biasv[4];
    #pragma unroll
    for (int q = 0; q < 4; ++q) biasv[q] = bsum[l * 1024 + q * 256 + u];
    const float pi = wci[u], pf = wcf[u], po = wco[u];
    float cst[4] = {0.f, 0.f, 0.f, 0.f};

    // exchange buffers
    unsigned long long* xs_send = xbuf + (size_t)(chunk * 2 + HALF) * 1024;
    const unsigned long long* xs_recv = xbuf + (size_t)(chunk * 2 + (1 - HALF)) * 1024;
    // receiver mapping: this thread owns words 2*tid, 2*tid+1
    const int w0i = 2 * tid, w1i = 2 * tid + 1;
    const int pu0 = 128 * (1 - HALF) + (w0i >> 3), pb0 = w0i & 7;
    const int pu1 = 128 * (1 - HALF) + (w1i >> 3), pb1 = w1i & 7;

    int cur = 0;
    __syncthreads();

    for (int t = 0; t < T; ++t) {
        // issue x_{t+1} load early (committed at end of step)
        float4 xn = make_float4(0.f, 0.f, 0.f, 0.f);
        const bool havex = (tid < 256) && (t + 1 < T);
        if (havex)
            xn = *(const float4*)(x + ((size_t)(b0 + (tid >> 4)) * T + (t + 1)) * I_DIM + 4 * (tid & 15));

        f32x4 acc[4];
        #pragma unroll
        for (int q = 0; q < 4; ++q)
            acc[q] = (f32x4){biasv[q], biasv[q], biasv[q], biasv[q]};

#define MK(kk) do {                                                                     \
        f16x8 a_ = *(const f16x8*)&vh[cur][lr][(kk) * 32 + lg * 8];                     \
        acc[0] = __builtin_amdgcn_mfma_f32_16x16x32_f16(a_, wreg[kk][0], acc[0], 0,0,0);\
        acc[1] = __builtin_amdgcn_mfma_f32_16x16x32_f16(a_, wreg[kk][1], acc[1], 0,0,0);\
        acc[2] = __builtin_amdgcn_mfma_f32_16x16x32_f16(a_, wreg[kk][2], acc[2], 0,0,0);\
        acc[3] = __builtin_amdgcn_mfma_f32_16x16x32_f16(a_, wreg[kk][3], acc[3], 0,0,0);\
    } while (0)

        // PHASE A: x part + own h-half (valid in vh[cur] at entry)
        MK(0); MK(1);
        if constexpr (HALF == 0) { MK(2); MK(3); MK(4); MK(5); }
        else                     { MK(6); MK(7); MK(8); MK(9); }

        // receive partner h_{t-1} (skip t=0: zeros already staged)
        if (t > 0) {
            unsigned long long w0 = __hip_atomic_load(&xs_recv[w0i], __ATOMIC_RELAXED,
                                                      __HIP_MEMORY_SCOPE_AGENT);
            unsigned long long w1 = __hip_atomic_load(&xs_recv[w1i], __ATOMIC_RELAXED,
                                                      __HIP_MEMORY_SCOPE_AGENT);
            while ((unsigned)(w0 >> 32) != (unsigned)t) {
                __builtin_amdgcn_s_sleep(1);
                w0 = __hip_atomic_load(&xs_recv[w0i], __ATOMIC_RELAXED,
                                       __HIP_MEMORY_SCOPE_AGENT);
            }
            while ((unsigned)(w1 >> 32) != (unsigned)t) {
                __builtin_amdgcn_s_sleep(1);
                w1 = __hip_atomic_load(&xs_recv[w1i], __ATOMIC_RELAXED,
                                       __HIP_MEMORY_SCOPE_AGENT);
            }
            uint32_t d0 = (uint32_t)w0, d1 = (uint32_t)w1;
            vh[cur][2 * pb0 + 0][I_DIM + pu0] = __builtin_bit_cast(_Float16, (uint16_t)d0);
            vh[cur][2 * pb0 + 1][I_DIM + pu0] = __builtin_bit_cast(_Float16, (uint16_t)(d0 >> 16));
            vh[cur][2 * pb1 + 0][I_DIM + pu1] = __builtin_bit_cast(_Float16, (uint16_t)d1);
            vh[cur][2 * pb1 + 1][I_DIM + pu1] = __builtin_bit_cast(_Float16, (uint16_t)(d1 >> 16));
        }
        __syncthreads();   // partner region of vh[cur] now valid

        // PHASE B: partner h-half
        if constexpr (HALF == 0) { MK(6); MK(7); MK(8); MK(9); }
        else                     { MK(2); MK(3); MK(4); MK(5); }
#undef MK

        // in-lane activation: 4 cells (batch lg*4+r, unit u)
        _Float16 h16[4];
        #pragma unroll
        for (int r = 0; r < 4; ++r) {
            int b = lg * 4 + r;
            float c  = cst[r];
            float i_ = sigmoidf(acc[0][r] + pi * c);
            float f_ = sigmoidf(acc[1][r] + pf * c);
            float g_ = tanh_fast(acc[2][r]);
            float cy = f_ * c + i_ * g_;
            float o_ = sigmoidf(acc[3][r] + po * cy);
            float hy = o_ * tanh_fast(cy);
            cst[r] = cy;
            h16[r] = (_Float16)hy;
            vh[cur ^ 1][b][I_DIM + u] = h16[r];
            hseq[((size_t)(b0 + b) * ST + toff + t) * H_DIM + u] = hy;
        }
        // send own h-half: 2 self-validating 64b words (tag = t+1)
        {
            unsigned long long tag = ((unsigned long long)(unsigned)(t + 1)) << 32;
            uint32_t d0 = (uint32_t)__builtin_bit_cast(uint16_t, h16[0])
                        | ((uint32_t)__builtin_bit_cast(uint16_t, h16[1]) << 16);
            uint32_t d1 = (uint32_t)__builtin_bit_cast(uint16_t, h16[2])
                        | ((uint32_t)__builtin_bit_cast(uint16_t, h16[3]) << 16);
            __hip_atomic_store(&xs_send[ul * 8 + 2 * lg + 0], d0 | tag,
                               __ATOMIC_RELAXED, __HIP_MEMORY_SCOPE_AGENT);
            __hip_atomic_store(&xs_send[ul * 8 + 2 * lg + 1], d1 | tag,
                               __ATOMIC_RELAXED, __HIP_MEMORY_SCOPE_AGENT);
        }
        // commit x_{t+1}
        if (havex) {
            f16x4 p = { (_Float16)xn.x, (_Float16)xn.y, (_Float16)xn.z, (_Float16)xn.w };
            *(f16x4*)&vh[cur ^ 1][tid >> 4][4 * (tid & 15)] = p;
        }
        __syncthreads();   // vh[cur^1] own+x complete
        cur ^= 1;
    }
}

__global__ __launch_bounds__(512, 2) void lstm_pair(
        const float* __restrict__ x1, const float* __restrict__ x2,
        const float* __restrict__ wci1, const float* __restrict__ wcf1, const float* __restrict__ wco1,
        const float* __restrict__ wci2, const float* __restrict__ wcf2, const float* __restrict__ wco2,
        const f16x8* __restrict__ Bp, const float* __restrict__ bsum,
        float* __restrict__ hseq, unsigned long long* __restrict__ xbuf) {
    __shared__ __align__(16) _Float16 vh[2][MB][VH_STRIDE];
    const int bid  = blockIdx.x;           // 0..31
    const int xcd  = bid & 7;
    const int half = (bid >> 3) & 1;
    const int chunk = (bid >> 4) * 8 + xcd;    // 0..15
    const int l    = chunk >> 3;
    const int b0   = (chunk & 7) * MB;
    const int T    = l ? S2 : S1;
    const int toff = l ? S1 : 0;
    const float* x   = l ? x2 : x1;
    const float* wci = l ? wci2 : wci1;
    const float* wcf = l ? wcf2 : wcf1;
    const float* wco = l ? wco2 : wco1;
    if (half == 0)
        lstm_body<0>(l, b0, T, toff, chunk, x, wci, wcf, wco, Bp, bsum, hseq, xbuf, vh);
    else
        lstm_body<1>(l, b0, T, toff, chunk, x, wci, wcf, wco, Bp, bsum, hseq, xbuf, vh);
}

// ---------------------------------------------------------------------------
// fc1 split-K partial GEMM (unchanged)
// ---------------------------------------------------------------------------
__global__ __launch_bounds__(256) void fc1_partial(const float* __restrict__ hseq,
                                                   const float* __restrict__ w,
                                                   float* __restrict__ part) {
    const int s  = blockIdx.x;          // 0..NSLICE-1
    const int k0 = s * KC;
    const int kend = (k0 + KC < F1) ? (k0 + KC) : F1;

    __shared__ float As[KCH][129];      // As[k][b]
    __shared__ float Bs[KCH][129];      // Bs[k][j]

    const int tid = threadIdx.x;
    const int tx = tid & 15;            // j block
    const int ty = tid >> 4;            // b block

    float acc[8][8];
    #pragma unroll
    for (int i = 0; i < 8; ++i)
        #pragma unroll
        for (int j = 0; j < 8; ++j) acc[i][j] = 0.f;

    for (int kk = k0; kk < kend; kk += KCH) {
        #pragma unroll
        for (int r = 0; r < 16; ++r) {
            int idx = r * 256 + tid;    // 0..4095
            int row = idx >> 5;
            int k   = idx & 31;
            int gk  = kk + k;
            float av = (gk < F1) ? hseq[(size_t)row * F1 + gk] : 0.f;
            float bv = (gk < F1) ? w[(size_t)row * F1 + gk] : 0.f;
            As[k][row] = av;
            Bs[k][row] = bv;
        }
        __syncthreads();

        #pragma unroll 8
        for (int k = 0; k < KCH; ++k) {
            float av[8], bv[8];
            #pragma unroll
            for (int i = 0; i < 8; ++i) av[i] = As[k][ty * 8 + i];
            #pragma unroll
            for (int j = 0; j < 8; ++j) bv[j] = Bs[k][tx * 8 + j];
            #pragma unroll
            for (int i = 0; i < 8; ++i)
                #pragma unroll
                for (int j = 0; j < 8; ++j)
                    acc[i][j] = fmaf(av[i], bv[j], acc[i][j]);
        }
        __syncthreads();
    }

    float* dst = part + (size_t)s * (BATCH * 128);
    #pragma unroll
    for (int i = 0; i < 8; ++i)
        #pragma unroll
        for (int j = 0; j < 8; ++j)
            dst[(size_t)(ty * 8 + i) * 128 + (tx * 8 + j)] = acc[i][j];
}

__global__ __launch_bounds__(256) void fc1_reduce(const float* __restrict__ part,
                                                  const float* __restrict__ fc1_b,
                                                  float* __restrict__ out1) {
    int flat = blockIdx.x * 256 + threadIdx.x;     // 0..16383
    float sum = 0.f;
    for (int i = 0; i < NSLICE; ++i)
        sum += part[(size_t)i * (BATCH * 128) + flat];
    int j = flat & 127;
    sum += fc1_b[j];
    out1[flat] = fmaxf(sum, 0.f);
}

__global__ __launch_bounds__(128) void fc2_kernel(const float* __restrict__ out1,
                                                  const float* __restrict__ fcw,
                                                  const float* __restrict__ fcb,
                                                  float* __restrict__ out) {
    int b = blockIdx.x;
    __shared__ float ro[128];
    int tid = threadIdx.x;
    ro[tid] = out1[(size_t)b * 128 + tid];
    __syncthreads();
    if (tid < NC) {
        float s = fcb[tid];
        #pragma unroll 8
        for (int j = 0; j < 128; ++j)
            s = fmaf(ro[j], fcw[(size_t)tid * 128 + j], s);
        out[(size_t)b * NC + tid] = s;
    }
}

// ---------------------------------------------------------------------------
extern "C" void kernel_launch(void* const* d_in, const int* in_sizes, int n_in,
                              void* d_out, int out_size, void* d_ws, size_t ws_size,
                              hipStream_t stream) {
    const float* rr_x  = (const float*)d_in[0];
    const float* rr_wv = (const float*)d_in[1];
    const float* w_ih1 = (const float*)d_in[2];
    const float* w_hh1 = (const float*)d_in[3];
    const float* b_ih1 = (const float*)d_in[4];
    const float* b_hh1 = (const float*)d_in[5];
    const float* wci1  = (const float*)d_in[6];
    const float* wcf1  = (const float*)d_in[7];
    const float* wco1  = (const float*)d_in[8];
    const float* w_ih2 = (const float*)d_in[9];
    const float* w_hh2 = (const float*)d_in[10];
    const float* b_ih2 = (const float*)d_in[11];
    const float* b_hh2 = (const float*)d_in[12];
    const float* wci2  = (const float*)d_in[13];
    const float* wcf2  = (const float*)d_in[14];
    const float* wco2  = (const float*)d_in[15];
    const float* fc1_w = (const float*)d_in[16];
    const float* fc1_b = (const float*)d_in[17];
    const float* fc_w  = (const float*)d_in[18];
    const float* fc_b  = (const float*)d_in[19];
    float* out = (float*)d_out;

    char* ws = (char*)d_ws;
    size_t off = 0;
    f16x8* Bp  = (f16x8*)(ws + off);  off += (size_t)2 * NKK * 64 * 64 * sizeof(f16x8); // 1.31 MB
    float* bsum = (float*)(ws + off); off += (size_t)2048 * sizeof(float);
    float* hseq = (float*)(ws + off); off += (size_t)BATCH * F1 * sizeof(float);        // 70.9 MB
    float* part = (float*)(ws + off); off += (size_t)NSLICE * BATCH * 128 * sizeof(float);
    float* out1 = (float*)(ws + off); off += (size_t)BATCH * 128 * sizeof(float);
    unsigned long long* xbuf = (unsigned long long*)(ws + off);
    off += (size_t)32 * 1024 * sizeof(unsigned long long);                              // 256 KB

    prep_pack_b<<<320, 256, 0, stream>>>(w_ih1, w_hh1, w_ih2, w_hh2, Bp);
    prep_bias<<<8, 256, 0, stream>>>(b_ih1, b_hh1, b_ih2, b_hh2, bsum);
    hipMemsetAsync(xbuf, 0, (size_t)32 * 1024 * sizeof(unsigned long long), stream);

    lstm_pair<<<32, 512, 0, stream>>>(rr_x, rr_wv,
                                      wci1, wcf1, wco1, wci2, wcf2, wco2,
                                      Bp, bsum, hseq, xbuf);

    fc1_partial<<<NSLICE, 256, 0, stream>>>(hseq, fc1_w, part);
    fc1_reduce<<<BATCH * 128 / 256, 256, 0, stream>>>(part, fc1_b, out1);
    fc2_kernel<<<BATCH, 128, 0, stream>>>(out1, fc_w, fc_b, out);
}

// Round 11
// 1412.326 us; speedup vs baseline: 11.8248x; 1.0705x over previous
//
#include <hip/hip_runtime.h>
#include <hip/hip_bf16.h>
#include <hip/hip_fp16.h>
#include <math.h>
#include <stdint.h>

// Problem constants
#define I_DIM 64
#define H_DIM 256
#define NC    10
#define S1    500
#define S2    41
#define BATCH 128
#define ST    (S1 + S2)          // 541
#define F1    (ST * H_DIM)       // 138496
#define KTOT  (I_DIM + H_DIM)    // 320
#define NKK   10                 // K-steps of 32
#define MB    16                 // batch rows per chunk
#define VH_STRIDE 328            // fp16 row stride for [x|h] (320 + 8 pad)

// fc1 split-K params
#define KC   512
#define KCH  32
#define NSLICE ((F1 + KC - 1) / KC)   // 271

typedef _Float16 f16x8 __attribute__((ext_vector_type(8)));
typedef _Float16 f16x4 __attribute__((ext_vector_type(4)));
typedef float    f32x4 __attribute__((ext_vector_type(4)));

__device__ __forceinline__ float sigmoidf(float x) {
    return 1.0f / (1.0f + __expf(-x));
}
__device__ __forceinline__ float tanh_fast(float x) {
    float e = __expf(2.0f * x);
    return 1.0f - 2.0f / (e + 1.0f);
}

// ---------------------------------------------------------------------------
// Pack [w_ih | w_hh] (fp32) into MFMA B-fragment order, fp16 (same as r6-r8):
//   Bp[ ((l*NKK + kk)*64 + ntg)*64 + lane ]  (one f16x8 per lane)
//   n = ntg*16 + (lane&15);  k = kk*32 + (lane>>4)*8 + e
// ---------------------------------------------------------------------------
__global__ __launch_bounds__(256) void prep_pack_b(
        const float* __restrict__ wih1, const float* __restrict__ whh1,
        const float* __restrict__ wih2, const float* __restrict__ whh2,
        f16x8* __restrict__ Bp) {
    int gid = blockIdx.x * 256 + threadIdx.x;      // 0..81919
    int lane = gid & 63;
    int frag = gid >> 6;                           // 0..1279
    int ntg  = frag & 63;
    int rest = frag >> 6;                          // 0..19
    int kk   = rest % NKK;
    int l    = rest / NKK;
    const float* wih = l ? wih2 : wih1;
    const float* whh = l ? whh2 : whh1;
    int n  = ntg * 16 + (lane & 15);               // gate row 0..1023
    int k0 = kk * 32 + (lane >> 4) * 8;
    f16x8 v;
    #pragma unroll
    for (int e = 0; e < 8; ++e) {
        int k = k0 + e;
        float f = (k < I_DIM) ? wih[(size_t)n * I_DIM + k]
                              : whh[(size_t)n * H_DIM + (k - I_DIM)];
        v[e] = (_Float16)f;
    }
    Bp[gid] = v;
}

__global__ __launch_bounds__(256) void prep_bias(
        const float* __restrict__ bih1, const float* __restrict__ bhh1,
        const float* __restrict__ bih2, const float* __restrict__ bhh2,
        float* __restrict__ bsum) {
    int gid = blockIdx.x * 256 + threadIdx.x;      // 0..2047
    if (gid >= 2048) return;
    int l = gid >> 10, n = gid & 1023;
    bsum[gid] = l ? (bih2[n] + bhh2[n]) : (bih1[n] + bhh1[n]);
}

// ---------------------------------------------------------------------------
// Pair-split MFMA peephole LSTM, register-resident weights, fence-free
// self-validating 64b exchange (tag+payload in one relaxed agent-scope word —
// r8-proven transport). r11 protocol changes, all latency-targeted:
//   * both poll words issued TOGETHER at step-top (before PHASE A), pinned by
//     sched_barrier(0); first use (tag check) comes after the PHASE A MFMAs,
//     so ~1 MALL RTT hides under compute.
//   * retry loop re-issues both loads each round (1 RTT per round, not 2).
//   * send issued immediately after activation, before any local bookkeeping.
// ---------------------------------------------------------------------------
template<int HALF>
__device__ __forceinline__ void lstm_body(
        int l, int b0, int T, int toff, int chunk,
        const float* __restrict__ x,
        const float* __restrict__ wci, const float* __restrict__ wcf, const float* __restrict__ wco,
        const f16x8* __restrict__ Bp, const float* __restrict__ bsum,
        float* __restrict__ hseq, unsigned long long* __restrict__ xbuf,
        _Float16 (*vh)[MB][VH_STRIDE]) {
    const int tid  = threadIdx.x;
    const int lane = tid & 63;
    const int wv   = tid >> 6;             // wave 0..7
    const int lr   = lane & 15;            // n-in-tile / batch row for A
    const int lg   = lane >> 4;            // k-group / batch-quad
    const int uw   = 8 * HALF + wv;        // global unit-tile 0..15
    const int u    = uw * 16 + lr;         // global unit 0..255
    const int ul   = 16 * wv + lr;         // unit local to this half 0..127

    // zero vh (h of buf0 must be 0 at t=0; partner region starts as 0)
    for (int i = tid; i < 2 * MB * VH_STRIDE / 2; i += 512) ((int*)vh)[i] = 0;
    __syncthreads();
    // stage x_0 (fp32 -> fp16)
    if (tid < 256) {
        int bb = tid >> 4, k4 = tid & 15;
        float4 v = *(const float4*)(x + ((size_t)(b0 + bb) * T + 0) * I_DIM + 4 * k4);
        f16x4 p = { (_Float16)v.x, (_Float16)v.y, (_Float16)v.z, (_Float16)v.w };
        *(f16x4*)&vh[0][bb][4 * k4] = p;
    }

    // one-time: this block's B-half into registers/AGPRs (40 frags)
    f16x8 wreg[NKK][4];
    #pragma unroll
    for (int kk = 0; kk < NKK; ++kk)
        #pragma unroll
        for (int q = 0; q < 4; ++q)
            wreg[kk][q] = Bp[(((size_t)l * NKK + kk) * 64 + q * 16 + uw) * 64 + lane];

    float biasv[4];
    #pragma unroll
    for (int q = 0; q < 4; ++q) biasv[q] = bsum[l * 1024 + q * 256 + u];
    const float pi = wci[u], pf = wcf[u], po = wco[u];
    float cst[4] = {0.f, 0.f, 0.f, 0.f};

    // exchange buffers
    unsigned long long* xs_send = xbuf + (size_t)(chunk * 2 + HALF) * 1024;
    const unsigned long long* xs_recv = xbuf + (size_t)(chunk * 2 + (1 - HALF)) * 1024;
    // receiver mapping: this thread owns words 2*tid, 2*tid+1
    const int w0i = 2 * tid, w1i = 2 * tid + 1;
    const int pu0 = 128 * (1 - HALF) + (w0i >> 3), pb0 = w0i & 7;
    const int pu1 = 128 * (1 - HALF) + (w1i >> 3), pb1 = w1i & 7;

    int cur = 0;
    __syncthreads();

    for (int t = 0; t < T; ++t) {
        // issue x_{t+1} load early (committed at end of step)
        float4 xn = make_float4(0.f, 0.f, 0.f, 0.f);
        const bool havex = (tid < 256) && (t + 1 < T);
        if (havex)
            xn = *(const float4*)(x + ((size_t)(b0 + (tid >> 4)) * T + (t + 1)) * I_DIM + 4 * (tid & 15));

        // issue BOTH partner polls now; consumed after PHASE A (~1 RTT hidden)
        unsigned long long w0 = 0, w1 = 0;
        if (t > 0) {
            w0 = __hip_atomic_load(&xs_recv[w0i], __ATOMIC_RELAXED, __HIP_MEMORY_SCOPE_AGENT);
            w1 = __hip_atomic_load(&xs_recv[w1i], __ATOMIC_RELAXED, __HIP_MEMORY_SCOPE_AGENT);
        }
        __builtin_amdgcn_sched_barrier(0);   // pin: loads stay issued here

        f32x4 acc[4];
        #pragma unroll
        for (int q = 0; q < 4; ++q)
            acc[q] = (f32x4){biasv[q], biasv[q], biasv[q], biasv[q]};

#define MK(kk) do {                                                                     \
        f16x8 a_ = *(const f16x8*)&vh[cur][lr][(kk) * 32 + lg * 8];                     \
        acc[0] = __builtin_amdgcn_mfma_f32_16x16x32_f16(a_, wreg[kk][0], acc[0], 0,0,0);\
        acc[1] = __builtin_amdgcn_mfma_f32_16x16x32_f16(a_, wreg[kk][1], acc[1], 0,0,0);\
        acc[2] = __builtin_amdgcn_mfma_f32_16x16x32_f16(a_, wreg[kk][2], acc[2], 0,0,0);\
        acc[3] = __builtin_amdgcn_mfma_f32_16x16x32_f16(a_, wreg[kk][3], acc[3], 0,0,0);\
    } while (0)

        // PHASE A: x part + own h-half (valid in vh[cur] at entry)
        MK(0); MK(1);
        if constexpr (HALF == 0) { MK(2); MK(3); MK(4); MK(5); }
        else                     { MK(6); MK(7); MK(8); MK(9); }

        // consume partner h_{t-1} (skip t=0: zeros already staged)
        if (t > 0) {
            const unsigned ut = (unsigned)t;
            int tries = 0;
            while ((((unsigned)(w0 >> 32)) != ut) | (((unsigned)(w1 >> 32)) != ut)) {
                if (++tries > 4) __builtin_amdgcn_s_sleep(1);
                w0 = __hip_atomic_load(&xs_recv[w0i], __ATOMIC_RELAXED, __HIP_MEMORY_SCOPE_AGENT);
                w1 = __hip_atomic_load(&xs_recv[w1i], __ATOMIC_RELAXED, __HIP_MEMORY_SCOPE_AGENT);
            }
            uint32_t d0 = (uint32_t)w0, d1 = (uint32_t)w1;
            vh[cur][2 * pb0 + 0][I_DIM + pu0] = __builtin_bit_cast(_Float16, (uint16_t)d0);
            vh[cur][2 * pb0 + 1][I_DIM + pu0] = __builtin_bit_cast(_Float16, (uint16_t)(d0 >> 16));
            vh[cur][2 * pb1 + 0][I_DIM + pu1] = __builtin_bit_cast(_Float16, (uint16_t)d1);
            vh[cur][2 * pb1 + 1][I_DIM + pu1] = __builtin_bit_cast(_Float16, (uint16_t)(d1 >> 16));
        }
        __syncthreads();   // partner region of vh[cur] now valid

        // PHASE B: partner h-half
        if constexpr (HALF == 0) { MK(6); MK(7); MK(8); MK(9); }
        else                     { MK(2); MK(3); MK(4); MK(5); }
#undef MK

        // in-lane activation: 4 cells (batch lg*4+r, unit u)
        _Float16 h16[4];
        float hyv[4];
        #pragma unroll
        for (int r = 0; r < 4; ++r) {
            float c  = cst[r];
            float i_ = sigmoidf(acc[0][r] + pi * c);
            float f_ = sigmoidf(acc[1][r] + pf * c);
            float g_ = tanh_fast(acc[2][r]);
            float cy = f_ * c + i_ * g_;
            float o_ = sigmoidf(acc[3][r] + po * cy);
            float hy = o_ * tanh_fast(cy);
            cst[r] = cy;
            hyv[r] = hy;
            h16[r] = (_Float16)hy;
        }
        // send own h-half FIRST (critical path): 2 self-validating words
        {
            unsigned long long tag = ((unsigned long long)(unsigned)(t + 1)) << 32;
            uint32_t d0 = (uint32_t)__builtin_bit_cast(uint16_t, h16[0])
                        | ((uint32_t)__builtin_bit_cast(uint16_t, h16[1]) << 16);
            uint32_t d1 = (uint32_t)__builtin_bit_cast(uint16_t, h16[2])
                        | ((uint32_t)__builtin_bit_cast(uint16_t, h16[3]) << 16);
            __hip_atomic_store(&xs_send[ul * 8 + 2 * lg + 0], d0 | tag,
                               __ATOMIC_RELAXED, __HIP_MEMORY_SCOPE_AGENT);
            __hip_atomic_store(&xs_send[ul * 8 + 2 * lg + 1], d1 | tag,
                               __ATOMIC_RELAXED, __HIP_MEMORY_SCOPE_AGENT);
        }
        __builtin_amdgcn_sched_barrier(0);   // send must not sink below bookkeeping
        // local bookkeeping
        #pragma unroll
        for (int r = 0; r < 4; ++r) {
            int b = lg * 4 + r;
            vh[cur ^ 1][b][I_DIM + u] = h16[r];
            hseq[((size_t)(b0 + b) * ST + toff + t) * H_DIM + u] = hyv[r];
        }
        // commit x_{t+1}
        if (havex) {
            f16x4 p = { (_Float16)xn.x, (_Float16)xn.y, (_Float16)xn.z, (_Float16)xn.w };
            *(f16x4*)&vh[cur ^ 1][tid >> 4][4 * (tid & 15)] = p;
        }
        __syncthreads();   // vh[cur^1] own+x complete
        cur ^= 1;
    }
}

__global__ __launch_bounds__(512, 2) void lstm_pair(
        const float* __restrict__ x1, const float* __restrict__ x2,
        const float* __restrict__ wci1, const float* __restrict__ wcf1, const float* __restrict__ wco1,
        const float* __restrict__ wci2, const float* __restrict__ wcf2, const float* __restrict__ wco2,
        const f16x8* __restrict__ Bp, const float* __restrict__ bsum,
        float* __restrict__ hseq, unsigned long long* __restrict__ xbuf) {
    __shared__ __align__(16) _Float16 vh[2][MB][VH_STRIDE];
    const int bid  = blockIdx.x;           // 0..31
    const int xcd  = bid & 7;
    const int half = (bid >> 3) & 1;
    const int chunk = (bid >> 4) * 8 + xcd;    // 0..15
    const int l    = chunk >> 3;
    const int b0   = (chunk & 7) * MB;
    const int T    = l ? S2 : S1;
    const int toff = l ? S1 : 0;
    const float* x   = l ? x2 : x1;
    const float* wci = l ? wci2 : wci1;
    const float* wcf = l ? wcf2 : wcf1;
    const float* wco = l ? wco2 : wco1;
    if (half == 0)
        lstm_body<0>(l, b0, T, toff, chunk, x, wci, wcf, wco, Bp, bsum, hseq, xbuf, vh);
    else
        lstm_body<1>(l, b0, T, toff, chunk, x, wci, wcf, wco, Bp, bsum, hseq, xbuf, vh);
}

// ---------------------------------------------------------------------------
// fc1 split-K partial GEMM (unchanged)
// ---------------------------------------------------------------------------
__global__ __launch_bounds__(256) void fc1_partial(const float* __restrict__ hseq,
                                                   const float* __restrict__ w,
                                                   float* __restrict__ part) {
    const int s  = blockIdx.x;          // 0..NSLICE-1
    const int k0 = s * KC;
    const int kend = (k0 + KC < F1) ? (k0 + KC) : F1;

    __shared__ float As[KCH][129];      // As[k][b]
    __shared__ float Bs[KCH][129];      // Bs[k][j]

    const int tid = threadIdx.x;
    const int tx = tid & 15;            // j block
    const int ty = tid >> 4;            // b block

    float acc[8][8];
    #pragma unroll
    for (int i = 0; i < 8; ++i)
        #pragma unroll
        for (int j = 0; j < 8; ++j) acc[i][j] = 0.f;

    for (int kk = k0; kk < kend; kk += KCH) {
        #pragma unroll
        for (int r = 0; r < 16; ++r) {
            int idx = r * 256 + tid;    // 0..4095
            int row = idx >> 5;
            int k   = idx & 31;
            int gk  = kk + k;
            float av = (gk < F1) ? hseq[(size_t)row * F1 + gk] : 0.f;
            float bv = (gk < F1) ? w[(size_t)row * F1 + gk] : 0.f;
            As[k][row] = av;
            Bs[k][row] = bv;
        }
        __syncthreads();

        #pragma unroll 8
        for (int k = 0; k < KCH; ++k) {
            float av[8], bv[8];
            #pragma unroll
            for (int i = 0; i < 8; ++i) av[i] = As[k][ty * 8 + i];
            #pragma unroll
            for (int j = 0; j < 8; ++j) bv[j] = Bs[k][tx * 8 + j];
            #pragma unroll
            for (int i = 0; i < 8; ++i)
                #pragma unroll
                for (int j = 0; j < 8; ++j)
                    acc[i][j] = fmaf(av[i], bv[j], acc[i][j]);
        }
        __syncthreads();
    }

    float* dst = part + (size_t)s * (BATCH * 128);
    #pragma unroll
    for (int i = 0; i < 8; ++i)
        #pragma unroll
        for (int j = 0; j < 8; ++j)
            dst[(size_t)(ty * 8 + i) * 128 + (tx * 8 + j)] = acc[i][j];
}

__global__ __launch_bounds__(256) void fc1_reduce(const float* __restrict__ part,
                                                  const float* __restrict__ fc1_b,
                                                  float* __restrict__ out1) {
    int flat = blockIdx.x * 256 + threadIdx.x;     // 0..16383
    float sum = 0.f;
    for (int i = 0; i < NSLICE; ++i)
        sum += part[(size_t)i * (BATCH * 128) + flat];
    int j = flat & 127;
    sum += fc1_b[j];
    out1[flat] = fmaxf(sum, 0.f);
}

__global__ __launch_bounds__(128) void fc2_kernel(const float* __restrict__ out1,
                                                  const float* __restrict__ fcw,
                                                  const float* __restrict__ fcb,
                                                  float* __restrict__ out) {
    int b = blockIdx.x;
    __shared__ float ro[128];
    int tid = threadIdx.x;
    ro[tid] = out1[(size_t)b * 128 + tid];
    __syncthreads();
    if (tid < NC) {
        float s = fcb[tid];
        #pragma unroll 8
        for (int j = 0; j < 128; ++j)
            s = fmaf(ro[j], fcw[(size_t)tid * 128 + j], s);
        out[(size_t)b * NC + tid] = s;
    }
}

// ---------------------------------------------------------------------------
extern "C" void kernel_launch(void* const* d_in, const int* in_sizes, int n_in,
                              void* d_out, int out_size, void* d_ws, size_t ws_size,
                              hipStream_t stream) {
    const float* rr_x  = (const float*)d_in[0];
    const float* rr_wv = (const float*)d_in[1];
    const float* w_ih1 = (const float*)d_in[2];
    const float* w_hh1 = (const float*)d_in[3];
    const float* b_ih1 = (const float*)d_in[4];
    const float* b_hh1 = (const float*)d_in[5];
    const float* wci1  = (const float*)d_in[6];
    const float* wcf1  = (const float*)d_in[7];
    const float* wco1  = (const float*)d_in[8];
    const float* w_ih2 = (const float*)d_in[9];
    const float* w_hh2 = (const float*)d_in[10];
    const float* b_ih2 = (const float*)d_in[11];
    const float* b_hh2 = (const float*)d_in[12];
    const float* wci2  = (const float*)d_in[13];
    const float* wcf2  = (const float*)d_in[14];
    const float* wco2  = (const float*)d_in[15];
    const float* fc1_w = (const float*)d_in[16];
    const float* fc1_b = (const float*)d_in[17];
    const float* fc_w  = (const float*)d_in[18];
    const float* fc_b  = (const float*)d_in[19];
    float* out = (float*)d_out;

    char* ws = (char*)d_ws;
    size_t off = 0;
    f16x8* Bp  = (f16x8*)(ws + off);  off += (size_t)2 * NKK * 64 * 64 * sizeof(f16x8); // 1.31 MB
    float* bsum = (float*)(ws + off); off += (size_t)2048 * sizeof(float);
    float* hseq = (float*)(ws + off); off += (size_t)BATCH * F1 * sizeof(float);        // 70.9 MB
    float* part = (float*)(ws + off); off += (size_t)NSLICE * BATCH * 128 * sizeof(float);
    float* out1 = (float*)(ws + off); off += (size_t)BATCH * 128 * sizeof(float);
    unsigned long long* xbuf = (unsigned long long*)(ws + off);
    off += (size_t)32 * 1024 * sizeof(unsigned long long);                              // 256 KB

    prep_pack_b<<<320, 256, 0, stream>>>(w_ih1, w_hh1, w_ih2, w_hh2, Bp);
    prep_bias<<<8, 256, 0, stream>>>(b_ih1, b_hh1, b_ih2, b_hh2, bsum);
    hipMemsetAsync(xbuf, 0, (size_t)32 * 1024 * sizeof(unsigned long long), stream);

    lstm_pair<<<32, 512, 0, stream>>>(rr_x, rr_wv,
                                      wci1, wcf1, wco1, wci2, wcf2, wco2,
                                      Bp, bsum, hseq, xbuf);

    fc1_partial<<<NSLICE, 256, 0, stream>>>(hseq, fc1_w, part);
    fc1_reduce<<<BATCH * 128 / 256, 256, 0, stream>>>(part, fc1_b, out1);
    fc2_kernel<<<BATCH, 128, 0, stream>>>(out1, fc_w, fc_b, out);
}